// Round 8
// baseline (335.281 us; speedup 1.0000x reference)
//
#include <hip/hip_runtime.h>
#include <cmath>

#define B_   2
#define L_   2048
#define DM_  512
#define DI_  1024
#define DS_  16
#define DTR_ 32
#define M_   (B_*L_)   // 4096
#define NC_  64        // chunks
#define CL_  32        // chunk length (NC_*CL_ == L_)
#define KS_  8         // GEMM2 split-K factor
#define LOG2E_ 1.44269504088896340736f

typedef __attribute__((ext_vector_type(8))) short short8;   // 8 bf16 = 4 VGPRs
typedef __attribute__((ext_vector_type(4))) float floatx4;  // MFMA acc

__device__ inline unsigned short f2bf(float f) {
  unsigned u = __float_as_uint(f);
  unsigned r = (u + 0x7fffu + ((u >> 16) & 1u)) >> 16;   // RNE
  return (unsigned short)r;
}
__device__ inline float bf2f(unsigned short u) {
  return __uint_as_float(((unsigned)u) << 16);
}

__device__ inline void gload_lds16(const unsigned short* g, unsigned short* l) {
  __builtin_amdgcn_global_load_lds(
      (const __attribute__((address_space(1))) void*)g,
      (__attribute__((address_space(3))) void*)l, 16, 0, 0);
}

// ---------------------------------------------------------------------------
// GEMM1 (bf16 MFMA, both dirs via grid.z): xz = x . Win^T, OUTPUT bf16.
// ---------------------------------------------------------------------------
__global__ __launch_bounds__(256) void gemm1_mfma_k(
    const unsigned short* __restrict__ A,
    const unsigned short* __restrict__ Wf, const unsigned short* __restrict__ Wr,
    unsigned short* __restrict__ Cf, unsigned short* __restrict__ Cr,
    int M, int N, int K)
{
  __shared__ unsigned short At[128 * 32];
  __shared__ unsigned short Wt[128 * 32];
  const unsigned short* W = blockIdx.z ? Wr : Wf;
  unsigned short* C = blockIdx.z ? Cr : Cf;
  const int tid  = threadIdx.x;
  const int w    = tid >> 6;
  const int lane = tid & 63;
  const int wm   = w >> 1, wn = w & 1;
  const int row0 = blockIdx.y * 128, col0 = blockIdx.x * 128;
  const int lrow  = lane >> 2;
  const int lkoff = (lane & 3) * 8;
  const int fr = lane & 15;
  const int fq = (lane >> 4) * 8;

  floatx4 acc[4][4];
#pragma unroll
  for (int i = 0; i < 4; ++i)
#pragma unroll
    for (int j = 0; j < 4; ++j)
#pragma unroll
      for (int r = 0; r < 4; ++r) acc[i][j][r] = 0.f;

  for (int k0 = 0; k0 < K; k0 += 32) {
#pragma unroll
    for (int j = 0; j < 2; ++j) {
      int r = w * 32 + j * 16;
      gload_lds16(A + (size_t)(row0 + r + lrow) * K + k0 + lkoff, At + r * 32);
      gload_lds16(W + (size_t)(col0 + r + lrow) * K + k0 + lkoff, Wt + r * 32);
    }
    __syncthreads();
    short8 af[4], bf[4];
#pragma unroll
    for (int i = 0; i < 4; ++i) {
      af[i] = *(const short8*)&At[(64 * wm + 16 * i + fr) * 32 + fq];
      bf[i] = *(const short8*)&Wt[(64 * wn + 16 * i + fr) * 32 + fq];
    }
#pragma unroll
    for (int i = 0; i < 4; ++i)
#pragma unroll
      for (int j = 0; j < 4; ++j)
        acc[i][j] = __builtin_amdgcn_mfma_f32_16x16x32_bf16(af[i], bf[j], acc[i][j], 0, 0, 0);
    __syncthreads();
  }
#pragma unroll
  for (int i = 0; i < 4; ++i) {
    int rg = row0 + 64 * wm + 16 * i + ((lane >> 4) << 2);
#pragma unroll
    for (int j = 0; j < 4; ++j) {
      int cg = col0 + 64 * wn + 16 * j + (lane & 15);
#pragma unroll
      for (int r = 0; r < 4; ++r)
        C[(size_t)(rg + r) * N + cg] = f2bf(acc[i][j][r]);
    }
  }
}

// ---------------------------------------------------------------------------
// GEMM4 (bf16 MFMA, split-source): partial[z] = y_z . Wout_z^T
// ---------------------------------------------------------------------------
__global__ __launch_bounds__(256) void gemm4_mfma_k(
    const unsigned short* __restrict__ ybf, const unsigned short* __restrict__ Woutbf,
    const unsigned short* __restrict__ ybr, const unsigned short* __restrict__ Woutbr,
    float* __restrict__ part)
{
  __shared__ unsigned short At[128 * 32];
  __shared__ unsigned short Wt[64 * 32];
  const int tid  = threadIdx.x;
  const int w    = tid >> 6;
  const int lane = tid & 63;
  const int col0 = blockIdx.x * 64;
  const int row0 = blockIdx.y * 128;
  const int z    = blockIdx.z;
  const unsigned short* A = z ? ybr : ybf;
  const unsigned short* W = z ? Woutbr : Woutbf;
  const int lrow  = lane >> 2;
  const int lkoff = (lane & 3) * 8;
  const int fr = lane & 15;
  const int fq = (lane >> 4) * 8;

  floatx4 acc[2][4];
#pragma unroll
  for (int i = 0; i < 2; ++i)
#pragma unroll
    for (int j = 0; j < 4; ++j)
#pragma unroll
      for (int r = 0; r < 4; ++r) acc[i][j][r] = 0.f;

  for (int k0 = 0; k0 < DI_; k0 += 32) {
#pragma unroll
    for (int j = 0; j < 2; ++j) {
      int r = w * 32 + j * 16;
      gload_lds16(A + (size_t)(row0 + r + lrow) * DI_ + k0 + lkoff, At + r * 32);
    }
    {
      int r = w * 16;
      gload_lds16(W + (size_t)(col0 + r + lrow) * DI_ + k0 + lkoff, Wt + r * 32);
    }
    __syncthreads();
    short8 af[2], bf[4];
#pragma unroll
    for (int i = 0; i < 2; ++i)
      af[i] = *(const short8*)&At[(32 * w + 16 * i + fr) * 32 + fq];
#pragma unroll
    for (int j = 0; j < 4; ++j)
      bf[j] = *(const short8*)&Wt[(16 * j + fr) * 32 + fq];
#pragma unroll
    for (int i = 0; i < 2; ++i)
#pragma unroll
      for (int j = 0; j < 4; ++j)
        acc[i][j] = __builtin_amdgcn_mfma_f32_16x16x32_bf16(af[i], bf[j], acc[i][j], 0, 0, 0);
    __syncthreads();
  }
  float* dst = part + (size_t)z * M_ * DM_;
#pragma unroll
  for (int i = 0; i < 2; ++i) {
    int rg = row0 + 32 * w + 16 * i + ((lane >> 4) << 2);
#pragma unroll
    for (int j = 0; j < 4; ++j) {
      int cg = col0 + 16 * j + (lane & 15);
#pragma unroll
      for (int r = 0; r < 4; ++r)
        dst[(size_t)(rg + r) * DM_ + cg] = acc[i][j][r];
    }
  }
}

// out = p0 + p1 (float4)
__global__ __launch_bounds__(256) void add2_k(
    const float* __restrict__ part, float* __restrict__ out)
{
  int g = blockIdx.x * 256 + threadIdx.x;
  float4 a = *(const float4*)(part + (size_t)g * 4);
  float4 b = *(const float4*)(part + (size_t)M_ * DM_ + (size_t)g * 4);
  float4 o = make_float4(a.x + b.x, a.y + b.y, a.z + b.z, a.w + b.w);
  *(float4*)(out + (size_t)g * 4) = o;
}

// ---------------------------------------------------------------------------
// GEMM2 (bf16 MFMA, split-K, both dirs): part[dir][ks][m][n].
// ---------------------------------------------------------------------------
__global__ __launch_bounds__(256) void gemm2_mfma_k(
    const unsigned short* __restrict__ xsbf, const unsigned short* __restrict__ xsbr,
    const unsigned short* __restrict__ Wxbf, const unsigned short* __restrict__ Wxbr,
    float* __restrict__ part)
{
  __shared__ unsigned short At[128 * 32];
  __shared__ unsigned short Wt[64 * 32];
  const int tid  = threadIdx.x;
  const int w    = tid >> 6;
  const int lane = tid & 63;
  const int ks   = blockIdx.x;
  const int row0 = blockIdx.y * 128;
  const int dir  = blockIdx.z;
  const unsigned short* A = dir ? xsbr : xsbf;
  const unsigned short* W = dir ? Wxbr : Wxbf;
  const int kbase = ks * (DI_ / KS_);
  const int lrow  = lane >> 2;
  const int lkoff = (lane & 3) * 8;
  const int fr = lane & 15;
  const int fq = (lane >> 4) * 8;

  floatx4 acc[2][4];
#pragma unroll
  for (int i = 0; i < 2; ++i)
#pragma unroll
    for (int j = 0; j < 4; ++j)
#pragma unroll
      for (int r = 0; r < 4; ++r) acc[i][j][r] = 0.f;

  for (int k0 = 0; k0 < DI_ / KS_; k0 += 32) {
#pragma unroll
    for (int j = 0; j < 2; ++j) {
      int r = w * 32 + j * 16;
      gload_lds16(A + (size_t)(row0 + r + lrow) * DI_ + kbase + k0 + lkoff, At + r * 32);
    }
    {
      int r = w * 16;
      gload_lds16(W + (size_t)(r + lrow) * DI_ + kbase + k0 + lkoff, Wt + r * 32);
    }
    __syncthreads();
    short8 af[2], bf[4];
#pragma unroll
    for (int i = 0; i < 2; ++i)
      af[i] = *(const short8*)&At[(32 * w + 16 * i + fr) * 32 + fq];
#pragma unroll
    for (int j = 0; j < 4; ++j)
      bf[j] = *(const short8*)&Wt[(16 * j + fr) * 32 + fq];
#pragma unroll
    for (int i = 0; i < 2; ++i)
#pragma unroll
      for (int j = 0; j < 4; ++j)
        acc[i][j] = __builtin_amdgcn_mfma_f32_16x16x32_bf16(af[i], bf[j], acc[i][j], 0, 0, 0);
    __syncthreads();
  }
  float* dst = part + (((size_t)dir * KS_ + ks) * M_) * 64;
#pragma unroll
  for (int i = 0; i < 2; ++i) {
    int rg = row0 + 32 * w + 16 * i + ((lane >> 4) << 2);
#pragma unroll
    for (int j = 0; j < 4; ++j) {
      int cg = 16 * j + (lane & 15);
#pragma unroll
      for (int r = 0; r < 4; ++r)
        dst[(size_t)(rg + r) * 64 + cg] = acc[i][j][r];
    }
  }
}

// Reduce split-K partials: xd[dir][m][n] = sum_ks part[dir][ks][m][n]
__global__ __launch_bounds__(256) void reduce_part_k(
    const float* __restrict__ part, float* __restrict__ xdf, float* __restrict__ xdr)
{
  int g = blockIdx.x * 256 + threadIdx.x;
  int n4  = g & 15;
  int m   = (g >> 4) & (M_ - 1);
  int dir = g >> 16;
  const float* p = part + ((size_t)dir * KS_ * M_ + m) * 64 + n4 * 4;
  float4 s = make_float4(0.f, 0.f, 0.f, 0.f);
#pragma unroll
  for (int ks = 0; ks < KS_; ++ks) {
    float4 v = *(const float4*)(p + (size_t)ks * M_ * 64);
    s.x += v.x; s.y += v.y; s.z += v.z; s.w += v.w;
  }
  float* xd = dir ? xdr : xdf;
  *(float4*)(xd + (size_t)m * 64 + n4 * 4) = s;
}

// ---------------------------------------------------------------------------
// Fused fp32 -> bf16 cast of 7 tensors
// ---------------------------------------------------------------------------
struct CastArgs {
  const float* src[7];
  unsigned short* dst[7];
  int start[7];
  int n[7];
};

__global__ __launch_bounds__(256) void cast_multi_k(CastArgs a, int total4)
{
  int g = blockIdx.x * 256 + threadIdx.x;
  if (g >= total4) return;
  int e = g * 4;
#pragma unroll 1
  for (int s = 0; s < 7; ++s) {
    if (e < a.start[s] + a.n[s]) {
      int off = e - a.start[s];
      float4 v = *(const float4*)(a.src[s] + off);
      ushort4 o;
      o.x = f2bf(v.x); o.y = f2bf(v.y); o.z = f2bf(v.z); o.w = f2bf(v.w);
      *(ushort4*)(a.dst[s] + off) = o;
      return;
    }
  }
}

// ---------------------------------------------------------------------------
// GEMM3 (fp32, both dirs via grid.z): dt = softplus(xd[:, :32] . Wdt^T + dtb)
// ---------------------------------------------------------------------------
__global__ __launch_bounds__(256) void gemm3_k(
    const float* __restrict__ A0, const float* __restrict__ A1,
    const float* __restrict__ W0, const float* __restrict__ W1,
    const float* __restrict__ b0, const float* __restrict__ b1,
    float* __restrict__ C0, float* __restrict__ C1)
{
  const float* A = blockIdx.z ? A1 : A0;
  const float* W = blockIdx.z ? W1 : W0;
  const float* bias = blockIdx.z ? b1 : b0;
  float* C = blockIdx.z ? C1 : C0;
  const int K = DTR_, lda = 64, ldw = DTR_, ldc = DI_;
  __shared__ __align__(16) float As[16][68];
  __shared__ __align__(16) float Ws[16][68];
  const int tid = threadIdx.x;
  const int tx = tid & 15;
  const int ty = tid >> 4;
  const int row0 = blockIdx.y * 64;
  const int col0 = blockIdx.x * 64;
  const int lm = tid >> 2;
  const int lk = (tid & 3) << 2;
  float acc[4][4] = {};
  for (int k0 = 0; k0 < K; k0 += 16) {
    float4 av = *(const float4*)(A + (size_t)(row0 + lm) * lda + k0 + lk);
    float4 wv = *(const float4*)(W + (size_t)(col0 + lm) * ldw + k0 + lk);
    As[lk+0][lm] = av.x; As[lk+1][lm] = av.y; As[lk+2][lm] = av.z; As[lk+3][lm] = av.w;
    Ws[lk+0][lm] = wv.x; Ws[lk+1][lm] = wv.y; Ws[lk+2][lm] = wv.z; Ws[lk+3][lm] = wv.w;
    __syncthreads();
#pragma unroll
    for (int kk = 0; kk < 16; ++kk) {
      float4 a = *(const float4*)&As[kk][ty << 2];
      float4 b = *(const float4*)&Ws[kk][tx << 2];
      float aa[4] = {a.x, a.y, a.z, a.w};
      float bb[4] = {b.x, b.y, b.z, b.w};
#pragma unroll
      for (int i = 0; i < 4; ++i)
#pragma unroll
        for (int j = 0; j < 4; ++j)
          acc[i][j] = fmaf(aa[i], bb[j], acc[i][j]);
    }
    __syncthreads();
  }
#pragma unroll
  for (int i = 0; i < 4; ++i) {
    int m = row0 + (ty << 2) + i;
#pragma unroll
    for (int j = 0; j < 4; ++j) {
      int n = col0 + (tx << 2) + j;
      float v = acc[i][j] + bias[n];
      v = (v > 20.f) ? v : log1pf(__expf(v));
      C[(size_t)m * ldc + n] = v;
    }
  }
}

// ---------------------------------------------------------------------------
// Depthwise conv(4) + bias + SiLU, both directions; bf16 in (xz) / bf16 out.
// ---------------------------------------------------------------------------
__global__ __launch_bounds__(256) void conv_silu_k(
    const unsigned short* __restrict__ xzbf, const unsigned short* __restrict__ xzbr,
    const float* __restrict__ cwf, const float* __restrict__ cbf,
    const float* __restrict__ cwr, const float* __restrict__ cbr,
    unsigned short* __restrict__ xsbf, unsigned short* __restrict__ xsbr)
{
  int bid = blockIdx.x;                 // [dir][b][t]
  int t   = bid & (L_ - 1);
  int b   = (bid >> 11) & (B_ - 1);
  int dir = bid >> 12;
  const unsigned short* xz = dir ? xzbr : xzbf;
  const float* cw = dir ? cwr : cwf;
  const float* cb = dir ? cbr : cbf;
  unsigned short* xsb = dir ? xsbr : xsbf;
  int d0 = threadIdx.x << 2;
  float wv[4][4];
#pragma unroll
  for (int i = 0; i < 4; ++i) {
    float4 w4 = *(const float4*)(cw + (size_t)(d0 + i) * 4);
    wv[i][0] = w4.x; wv[i][1] = w4.y; wv[i][2] = w4.z; wv[i][3] = w4.w;
  }
  float4 cbv = *(const float4*)(cb + d0);
  float acc[4] = {cbv.x, cbv.y, cbv.z, cbv.w};
#pragma unroll
  for (int j = 0; j < 4; ++j) {
    int tt = dir ? (t + 3 - j) : (t - 3 + j);
    if (tt >= 0 && tt < L_) {
      ushort4 v = *(const ushort4*)(xz + ((size_t)b * L_ + tt) * 2048 + d0);
      acc[0] = fmaf(wv[0][j], bf2f(v.x), acc[0]);
      acc[1] = fmaf(wv[1][j], bf2f(v.y), acc[1]);
      acc[2] = fmaf(wv[2][j], bf2f(v.z), acc[2]);
      acc[3] = fmaf(wv[3][j], bf2f(v.w), acc[3]);
    }
  }
  float4 o;
  o.x = acc[0] * __builtin_amdgcn_rcpf(1.f + __expf(-acc[0]));
  o.y = acc[1] * __builtin_amdgcn_rcpf(1.f + __expf(-acc[1]));
  o.z = acc[2] * __builtin_amdgcn_rcpf(1.f + __expf(-acc[2]));
  o.w = acc[3] * __builtin_amdgcn_rcpf(1.f + __expf(-acc[3]));
  ushort4 ob;
  ob.x = f2bf(o.x); ob.y = f2bf(o.y); ob.z = f2bf(o.z); ob.w = f2bf(o.w);
  *(ushort4*)(xsb + ((size_t)b * L_ + t) * DI_ + d0) = ob;
}

// ---------------------------------------------------------------------------
// Scan pass A: per (dir,b,d,chunk): E = local end state, dts = sum dt.
// (No P buffer — prefix recomputes it from dtsum.)
// ---------------------------------------------------------------------------
__global__ __launch_bounds__(256) void scan_passA_k(
    const float* __restrict__ dtf, const float* __restrict__ dtr,
    const unsigned short* __restrict__ xsbf, const unsigned short* __restrict__ xsbr,
    const float* __restrict__ xdf, const float* __restrict__ xdr,
    const float* __restrict__ Alogf, const float* __restrict__ Alogr,
    float* __restrict__ E, float* __restrict__ dts)
{
  __shared__ float bS[CL_][16];         // B row per chunk step
  int bid  = blockIdx.x;               // [dir][b][c][dgrp]
  int dgrp = bid & 3;
  int c    = (bid >> 2) & (NC_ - 1);
  int b    = (bid >> 8) & 1;
  int dir  = bid >> 9;
  int d    = (dgrp << 8) + threadIdx.x;
  const float* dt = dir ? dtr : dtf;
  const unsigned short* xs = dir ? xsbr : xsbf;
  const float* xd = dir ? xdr : xdf;
  const float* Al = dir ? Alogr : Alogf;
  if (threadIdx.x < CL_ * 4) {
    int li = threadIdx.x >> 2;
    int lc = threadIdx.x & 3;
    *(float4*)&bS[li][lc * 4] =
        *(const float4*)(xd + ((size_t)b * L_ + c * CL_ + li) * 64 + 32 + lc * 4);
  }
  float Ai2[16];
#pragma unroll
  for (int s = 0; s < 16; ++s) Ai2[s] = -__expf(Al[(size_t)d * 16 + s]) * LOG2E_;
  float h[16];
#pragma unroll
  for (int s = 0; s < 16; ++s) h[s] = 0.f;
  int t0 = c * CL_ + (dir ? CL_ - 1 : 0);
  const long sdt = (dir ? -1L : 1L) * DI_;
  const float* dtp = dt + ((size_t)b * L_ + t0) * DI_ + d;
  const unsigned short* xsp = xs + ((size_t)b * L_ + t0) * DI_ + d;
  float dtsum = 0.f;
  __syncthreads();
  float dcur = *dtp;
  unsigned short xcur = *xsp;
#pragma unroll 2
  for (int i = 0; i < CL_; ++i) {
    float dnxt = 0.f; unsigned short xnxt = 0;
    if (i + 1 < CL_) { dnxt = dtp[sdt]; xnxt = xsp[sdt]; }
    int row = dir ? (CL_ - 1 - i) : i;
    float Bv[16];
#pragma unroll
    for (int q = 0; q < 4; ++q) {
      float4 bq = *(const float4*)&bS[row][4 * q];
      Bv[4*q] = bq.x; Bv[4*q+1] = bq.y; Bv[4*q+2] = bq.z; Bv[4*q+3] = bq.w;
    }
    float xv  = bf2f(xcur);
    float dtx = dcur * xv;
    dtsum += dcur;
#pragma unroll
    for (int s = 0; s < 16; ++s) {
      float dA = exp2f(dcur * Ai2[s]);
      h[s] = fmaf(dA, h[s], dtx * Bv[s]);
    }
    dcur = dnxt; xcur = xnxt; dtp += sdt; xsp += sdt;
  }
  size_t base = ((((size_t)dir * B_ + b) * NC_ + c) * DI_ + d) * 16;
#pragma unroll
  for (int q = 0; q < 4; ++q)
    *(float4*)(E + base + q * 4) = make_float4(h[4*q], h[4*q+1], h[4*q+2], h[4*q+3]);
  dts[(((size_t)dir * B_ + b) * NC_ + c) * DI_ + d] = dtsum;
}

// ---------------------------------------------------------------------------
// Chunk prefix: Hin[c] = state entering chunk c. P recomputed from dtsum.
// ---------------------------------------------------------------------------
__global__ __launch_bounds__(256) void scan_prefix_k(
    const float* __restrict__ E, const float* __restrict__ dts,
    const float* __restrict__ Alogf, const float* __restrict__ Alogr,
    float* __restrict__ Hin)
{
  int gid = blockIdx.x * 256 + threadIdx.x;   // [dir][b][d][s]
  int s   = gid & 15;
  int d   = (gid >> 4) & (DI_ - 1);
  int b   = (gid >> 14) & 1;
  int dir = gid >> 15;
  const float* Al = dir ? Alogr : Alogf;
  float Ai2 = -__expf(Al[(size_t)d * 16 + s]) * LOG2E_;
  size_t eb  = (((size_t)dir * B_ + b) * NC_) * DI_ * 16 + (size_t)d * 16 + s;
  size_t db2 = (((size_t)dir * B_ + b) * NC_) * DI_ + d;
  float h = 0.f;
  if (!dir) {
    for (int c = 0; c < NC_; ++c) {
      size_t idx = eb + (size_t)c * DI_ * 16;
      Hin[idx] = h;
      float Pv = exp2f(dts[db2 + (size_t)c * DI_] * Ai2);
      h = fmaf(Pv, h, E[idx]);
    }
  } else {
    for (int c = NC_ - 1; c >= 0; --c) {
      size_t idx = eb + (size_t)c * DI_ * 16;
      Hin[idx] = h;
      float Pv = exp2f(dts[db2 + (size_t)c * DI_] * Ai2);
      h = fmaf(Pv, h, E[idx]);
    }
  }
}

// ---------------------------------------------------------------------------
// Scan pass C: replay chunk from Hin, y = (sum_s h*C + xs*Dp) * silu(z) -> bf16
// ---------------------------------------------------------------------------
__global__ __launch_bounds__(256) void scan_passC_k(
    const float* __restrict__ dtf, const float* __restrict__ dtr,
    const unsigned short* __restrict__ xsbf, const unsigned short* __restrict__ xsbr,
    const float* __restrict__ xdf, const float* __restrict__ xdr,
    const unsigned short* __restrict__ xzbf, const unsigned short* __restrict__ xzbr,
    const float* __restrict__ Alogf, const float* __restrict__ Alogr,
    const float* __restrict__ Dpf, const float* __restrict__ Dpr,
    const float* __restrict__ Hin,
    unsigned short* __restrict__ ybf, unsigned short* __restrict__ ybr)
{
  __shared__ float bcS[CL_][32];        // B(16)+C(16) per chunk step
  int bid  = blockIdx.x;
  int dgrp = bid & 3;
  int c    = (bid >> 2) & (NC_ - 1);
  int b    = (bid >> 8) & 1;
  int dir  = bid >> 9;
  int d    = (dgrp << 8) + threadIdx.x;
  const float* dt  = dir ? dtr : dtf;
  const unsigned short* xs = dir ? xsbr : xsbf;
  const float* xd  = dir ? xdr : xdf;
  const unsigned short* xz = dir ? xzbr : xzbf;
  const float* Al  = dir ? Alogr : Alogf;
  unsigned short* yb = dir ? ybr : ybf;
  float Dpv = (dir ? Dpr : Dpf)[d];
  {
    int li = threadIdx.x >> 3;
    int lc = threadIdx.x & 7;
    *(float4*)&bcS[li][lc * 4] =
        *(const float4*)(xd + ((size_t)b * L_ + c * CL_ + li) * 64 + 32 + lc * 4);
  }
  float Ai2[16];
#pragma unroll
  for (int s = 0; s < 16; ++s) Ai2[s] = -__expf(Al[(size_t)d * 16 + s]) * LOG2E_;
  size_t hb = ((((size_t)dir * B_ + b) * NC_ + c) * DI_ + d) * 16;
  float h[16];
#pragma unroll
  for (int q = 0; q < 4; ++q) {
    float4 hv = *(const float4*)(Hin + hb + q * 4);
    h[4*q] = hv.x; h[4*q+1] = hv.y; h[4*q+2] = hv.z; h[4*q+3] = hv.w;
  }
  int t0 = c * CL_ + (dir ? CL_ - 1 : 0);
  const long sdt = (dir ? -1L : 1L) * DI_;
  const long sz_ = (dir ? -1L : 1L) * 2048;
  const float* dtp = dt + ((size_t)b * L_ + t0) * DI_ + d;
  const unsigned short* xsp = xs + ((size_t)b * L_ + t0) * DI_ + d;
  const unsigned short* zp = xz + ((size_t)b * L_ + t0) * 2048 + DI_ + d;
  unsigned short* ybp = yb + ((size_t)b * L_ + t0) * DI_ + d;
  __syncthreads();
  float dcur = *dtp;
  unsigned short xcur = *xsp;
  unsigned short zcur = *zp;
#pragma unroll 2
  for (int i = 0; i < CL_; ++i) {
    float dnxt = 0.f; unsigned short xnxt = 0, znxt = 0;
    if (i + 1 < CL_) { dnxt = dtp[sdt]; xnxt = xsp[sdt]; znxt = zp[sz_]; }
    int row = dir ? (CL_ - 1 - i) : i;
    float Bv[16], Cv[16];
#pragma unroll
    for (int q = 0; q < 4; ++q) {
      float4 bq = *(const float4*)&bcS[row][4 * q];
      float4 cq = *(const float4*)&bcS[row][16 + 4 * q];
      Bv[4*q] = bq.x; Bv[4*q+1] = bq.y; Bv[4*q+2] = bq.z; Bv[4*q+3] = bq.w;
      Cv[4*q] = cq.x; Cv[4*q+1] = cq.y; Cv[4*q+2] = cq.z; Cv[4*q+3] = cq.w;
    }
    float xv  = bf2f(xcur);
    float z   = bf2f(zcur);
    float dtx = dcur * xv;
    float yacc = 0.f;
#pragma unroll
    for (int s = 0; s < 16; ++s) {
      float dA = exp2f(dcur * Ai2[s]);
      h[s] = fmaf(dA, h[s], dtx * Bv[s]);
      yacc = fmaf(h[s], Cv[s], yacc);
    }
    float yv = fmaf(xv, Dpv, yacc);
    float sz = z * __builtin_amdgcn_rcpf(1.f + __expf(-z));
    *ybp = f2bf(yv * sz);
    dcur = dnxt; xcur = xnxt; zcur = znxt;
    dtp += sdt; xsp += sdt; zp += sz_; ybp += sdt;
  }
}

// ---------------------------------------------------------------------------
extern "C" void kernel_launch(void* const* d_in, const int* in_sizes, int n_in,
                              void* d_out, int out_size, void* d_ws, size_t ws_size,
                              hipStream_t stream)
{
  const float* x       = (const float*)d_in[0];
  const float* Win_f   = (const float*)d_in[1];
  const float* convw_f = (const float*)d_in[2];
  const float* convb_f = (const float*)d_in[3];
  const float* Wx_f    = (const float*)d_in[4];
  const float* Wdt_f   = (const float*)d_in[5];
  const float* dtb_f   = (const float*)d_in[6];
  const float* Alog_f  = (const float*)d_in[7];
  const float* Dp_f    = (const float*)d_in[8];
  const float* Wout_f  = (const float*)d_in[9];
  const float* Win_r   = (const float*)d_in[10];
  const float* convw_r = (const float*)d_in[11];
  const float* convb_r = (const float*)d_in[12];
  const float* Wx_r    = (const float*)d_in[13];
  const float* Wdt_r   = (const float*)d_in[14];
  const float* dtb_r   = (const float*)d_in[15];
  const float* Alog_r  = (const float*)d_in[16];
  const float* Dp_r    = (const float*)d_in[17];
  const float* Wout_r  = (const float*)d_in[18];
  float* out = (float*)d_out;

  float* ws  = (float*)d_ws;
  float* xdf = ws;
  float* xdr = xdf + (size_t)M_ * 64;
  float* dtf = xdr + (size_t)M_ * 64;
  float* dtr = dtf + (size_t)M_ * DI_;
  float* Eb  = dtr + (size_t)M_ * DI_;                   // alias: GEMM2/GEMM4 partials
  float* Hb  = Eb + (size_t)2 * B_ * NC_ * DI_ * 16;
  float* dtsb = Hb + (size_t)2 * B_ * NC_ * DI_ * 16;
  float* part2 = Eb;   // GEMM2 partials (4.2M floats), dead before E written
  float* part4 = Eb;   // GEMM4 partials (4.2M floats), E dead after prefix
  unsigned short* xzbf    = (unsigned short*)(dtsb + (size_t)2 * B_ * NC_ * DI_);
  unsigned short* xzbr    = xzbf + (size_t)M_ * 2048;
  unsigned short* xb      = xzbr + (size_t)M_ * 2048;
  unsigned short* Winb_f  = xb + (size_t)M_ * DM_;
  unsigned short* Winb_r  = Winb_f + (size_t)2048 * DM_;
  unsigned short* Woutb_f = Winb_r + (size_t)2048 * DM_;
  unsigned short* Woutb_r = Woutb_f + (size_t)DM_ * DI_;
  unsigned short* ybf     = Woutb_r + (size_t)DM_ * DI_;
  unsigned short* ybr     = ybf + (size_t)M_ * DI_;
  unsigned short* xsbf    = ybr + (size_t)M_ * DI_;
  unsigned short* xsbr    = xsbf + (size_t)M_ * DI_;
  unsigned short* Wxb_f   = xsbr + (size_t)M_ * DI_;
  unsigned short* Wxb_r   = Wxb_f + (size_t)64 * DI_;

  dim3 blk(256);

  // cast x, Win_f/r, Wout_f/r, Wx_f/r to bf16
  {
    CastArgs ca;
    ca.src[0] = x;      ca.dst[0] = xb;      ca.n[0] = M_ * DM_;
    ca.src[1] = Win_f;  ca.dst[1] = Winb_f;  ca.n[1] = 2048 * DM_;
    ca.src[2] = Win_r;  ca.dst[2] = Winb_r;  ca.n[2] = 2048 * DM_;
    ca.src[3] = Wout_f; ca.dst[3] = Woutb_f; ca.n[3] = DM_ * DI_;
    ca.src[4] = Wout_r; ca.dst[4] = Woutb_r; ca.n[4] = DM_ * DI_;
    ca.src[5] = Wx_f;   ca.dst[5] = Wxb_f;   ca.n[5] = 64 * DI_;
    ca.src[6] = Wx_r;   ca.dst[6] = Wxb_r;   ca.n[6] = 64 * DI_;
    int st = 0;
    for (int s = 0; s < 7; ++s) { ca.start[s] = st; st += ca.n[s]; }
    int total4 = st / 4;
    cast_multi_k<<<(total4 + 255) / 256, blk, 0, stream>>>(ca, total4);
  }

  // GEMM1 (bf16 MFMA, both dirs): xz = x . Win^T -> bf16
  gemm1_mfma_k<<<dim3(2048 / 128, M_ / 128, 2), blk, 0, stream>>>(
      xb, Winb_f, Winb_r, xzbf, xzbr, M_, 2048, DM_);

  // conv + silu (both dirs), bf16 in/out
  conv_silu_k<<<2 * B_ * L_, blk, 0, stream>>>(xzbf, xzbr, convw_f, convb_f,
      convw_r, convb_r, xsbf, xsbr);

  // GEMM2 (bf16 MFMA split-K, both dirs) + reduce
  gemm2_mfma_k<<<dim3(KS_, M_ / 128, 2), blk, 0, stream>>>(
      xsbf, xsbr, Wxb_f, Wxb_r, part2);
  reduce_part_k<<<(2 * M_ * 16) / 256, blk, 0, stream>>>(part2, xdf, xdr);

  // GEMM3 (fp32, both dirs): dt = softplus(x_dbl[:, :32] . Wdt^T + dtb)
  gemm3_k<<<dim3(DI_ / 64, M_ / 64, 2), blk, 0, stream>>>(
      xdf, xdr, Wdt_f, Wdt_r, dtb_f, dtb_r, dtf, dtr);

  // chunked scan (A -> prefix -> C), P recomputed from dtsum
  scan_passA_k<<<2 * B_ * NC_ * 4, blk, 0, stream>>>(dtf, dtr, xsbf, xsbr,
      xdf, xdr, Alog_f, Alog_r, Eb, dtsb);
  scan_prefix_k<<<(2 * B_ * DI_ * 16) / 256, blk, 0, stream>>>(
      Eb, dtsb, Alog_f, Alog_r, Hb);
  scan_passC_k<<<2 * B_ * NC_ * 4, blk, 0, stream>>>(dtf, dtr, xsbf, xsbr,
      xdf, xdr, xzbf, xzbr, Alog_f, Alog_r, Dp_f, Dp_r, Hb, ybf, ybr);

  // GEMM4 (bf16 MFMA, split-source partials) + add
  gemm4_mfma_k<<<dim3(DM_ / 64, M_ / 128, 2), blk, 0, stream>>>(
      ybf, Woutb_f, ybr, Woutb_r, part4);
  add2_k<<<(M_ * DM_ / 4) / 256, blk, 0, stream>>>(part4, out);
}

// Round 9
// 302.140 us; speedup vs baseline: 1.1097x; 1.1097x over previous
//
#include <hip/hip_runtime.h>
#include <cmath>

#define B_   2
#define L_   2048
#define DM_  512
#define DI_  1024
#define DS_  16
#define DTR_ 32
#define M_   (B_*L_)   // 4096
#define NC_  64        // chunks
#define CL_  32        // chunk length (NC_*CL_ == L_)
#define KS_  8         // GEMM2 split-K factor
#define LOG2E_ 1.44269504088896340736f

typedef __attribute__((ext_vector_type(8))) short short8;   // 8 bf16 = 4 VGPRs
typedef __attribute__((ext_vector_type(4))) float floatx4;  // MFMA acc

__device__ inline unsigned short f2bf(float f) {
  unsigned u = __float_as_uint(f);
  unsigned r = (u + 0x7fffu + ((u >> 16) & 1u)) >> 16;   // RNE
  return (unsigned short)r;
}
__device__ inline float bf2f(unsigned short u) {
  return __uint_as_float(((unsigned)u) << 16);
}
// raw v_exp_f32 (2^x) — exp2f() is the slow libm path, do NOT use it
__device__ inline float fexp2(float x) { return __builtin_amdgcn_exp2f(x); }

__device__ inline void gload_lds16(const unsigned short* g, unsigned short* l) {
  __builtin_amdgcn_global_load_lds(
      (const __attribute__((address_space(1))) void*)g,
      (__attribute__((address_space(3))) void*)l, 16, 0, 0);
}

// ---------------------------------------------------------------------------
// GEMM1 (bf16 MFMA, both dirs via grid.z): xz = x . Win^T, OUTPUT bf16.
// ---------------------------------------------------------------------------
__global__ __launch_bounds__(256) void gemm1_mfma_k(
    const unsigned short* __restrict__ A,
    const unsigned short* __restrict__ Wf, const unsigned short* __restrict__ Wr,
    unsigned short* __restrict__ Cf, unsigned short* __restrict__ Cr,
    int M, int N, int K)
{
  __shared__ unsigned short At[128 * 32];
  __shared__ unsigned short Wt[128 * 32];
  const unsigned short* W = blockIdx.z ? Wr : Wf;
  unsigned short* C = blockIdx.z ? Cr : Cf;
  const int tid  = threadIdx.x;
  const int w    = tid >> 6;
  const int lane = tid & 63;
  const int wm   = w >> 1, wn = w & 1;
  const int row0 = blockIdx.y * 128, col0 = blockIdx.x * 128;
  const int lrow  = lane >> 2;
  const int lkoff = (lane & 3) * 8;
  const int fr = lane & 15;
  const int fq = (lane >> 4) * 8;

  floatx4 acc[4][4];
#pragma unroll
  for (int i = 0; i < 4; ++i)
#pragma unroll
    for (int j = 0; j < 4; ++j)
#pragma unroll
      for (int r = 0; r < 4; ++r) acc[i][j][r] = 0.f;

  for (int k0 = 0; k0 < K; k0 += 32) {
#pragma unroll
    for (int j = 0; j < 2; ++j) {
      int r = w * 32 + j * 16;
      gload_lds16(A + (size_t)(row0 + r + lrow) * K + k0 + lkoff, At + r * 32);
      gload_lds16(W + (size_t)(col0 + r + lrow) * K + k0 + lkoff, Wt + r * 32);
    }
    __syncthreads();
    short8 af[4], bf[4];
#pragma unroll
    for (int i = 0; i < 4; ++i) {
      af[i] = *(const short8*)&At[(64 * wm + 16 * i + fr) * 32 + fq];
      bf[i] = *(const short8*)&Wt[(64 * wn + 16 * i + fr) * 32 + fq];
    }
#pragma unroll
    for (int i = 0; i < 4; ++i)
#pragma unroll
      for (int j = 0; j < 4; ++j)
        acc[i][j] = __builtin_amdgcn_mfma_f32_16x16x32_bf16(af[i], bf[j], acc[i][j], 0, 0, 0);
    __syncthreads();
  }
#pragma unroll
  for (int i = 0; i < 4; ++i) {
    int rg = row0 + 64 * wm + 16 * i + ((lane >> 4) << 2);
#pragma unroll
    for (int j = 0; j < 4; ++j) {
      int cg = col0 + 64 * wn + 16 * j + (lane & 15);
#pragma unroll
      for (int r = 0; r < 4; ++r)
        C[(size_t)(rg + r) * N + cg] = f2bf(acc[i][j][r]);
    }
  }
}

// ---------------------------------------------------------------------------
// GEMM4 (bf16 MFMA, split-source): partial[z] = y_z . Wout_z^T
// ---------------------------------------------------------------------------
__global__ __launch_bounds__(256) void gemm4_mfma_k(
    const unsigned short* __restrict__ ybf, const unsigned short* __restrict__ Woutbf,
    const unsigned short* __restrict__ ybr, const unsigned short* __restrict__ Woutbr,
    float* __restrict__ part)
{
  __shared__ unsigned short At[128 * 32];
  __shared__ unsigned short Wt[64 * 32];
  const int tid  = threadIdx.x;
  const int w    = tid >> 6;
  const int lane = tid & 63;
  const int col0 = blockIdx.x * 64;
  const int row0 = blockIdx.y * 128;
  const int z    = blockIdx.z;
  const unsigned short* A = z ? ybr : ybf;
  const unsigned short* W = z ? Woutbr : Woutbf;
  const int lrow  = lane >> 2;
  const int lkoff = (lane & 3) * 8;
  const int fr = lane & 15;
  const int fq = (lane >> 4) * 8;

  floatx4 acc[2][4];
#pragma unroll
  for (int i = 0; i < 2; ++i)
#pragma unroll
    for (int j = 0; j < 4; ++j)
#pragma unroll
      for (int r = 0; r < 4; ++r) acc[i][j][r] = 0.f;

  for (int k0 = 0; k0 < DI_; k0 += 32) {
#pragma unroll
    for (int j = 0; j < 2; ++j) {
      int r = w * 32 + j * 16;
      gload_lds16(A + (size_t)(row0 + r + lrow) * DI_ + k0 + lkoff, At + r * 32);
    }
    {
      int r = w * 16;
      gload_lds16(W + (size_t)(col0 + r + lrow) * DI_ + k0 + lkoff, Wt + r * 32);
    }
    __syncthreads();
    short8 af[2], bf[4];
#pragma unroll
    for (int i = 0; i < 2; ++i)
      af[i] = *(const short8*)&At[(32 * w + 16 * i + fr) * 32 + fq];
#pragma unroll
    for (int j = 0; j < 4; ++j)
      bf[j] = *(const short8*)&Wt[(16 * j + fr) * 32 + fq];
#pragma unroll
    for (int i = 0; i < 2; ++i)
#pragma unroll
      for (int j = 0; j < 4; ++j)
        acc[i][j] = __builtin_amdgcn_mfma_f32_16x16x32_bf16(af[i], bf[j], acc[i][j], 0, 0, 0);
    __syncthreads();
  }
  float* dst = part + (size_t)z * M_ * DM_;
#pragma unroll
  for (int i = 0; i < 2; ++i) {
    int rg = row0 + 32 * w + 16 * i + ((lane >> 4) << 2);
#pragma unroll
    for (int j = 0; j < 4; ++j) {
      int cg = col0 + 16 * j + (lane & 15);
#pragma unroll
      for (int r = 0; r < 4; ++r)
        dst[(size_t)(rg + r) * DM_ + cg] = acc[i][j][r];
    }
  }
}

// out = p0 + p1 (float4)
__global__ __launch_bounds__(256) void add2_k(
    const float* __restrict__ part, float* __restrict__ out)
{
  int g = blockIdx.x * 256 + threadIdx.x;
  float4 a = *(const float4*)(part + (size_t)g * 4);
  float4 b = *(const float4*)(part + (size_t)M_ * DM_ + (size_t)g * 4);
  float4 o = make_float4(a.x + b.x, a.y + b.y, a.z + b.z, a.w + b.w);
  *(float4*)(out + (size_t)g * 4) = o;
}

// ---------------------------------------------------------------------------
// GEMM2 (bf16 MFMA, split-K, both dirs): part[dir][ks][m][n].
// ---------------------------------------------------------------------------
__global__ __launch_bounds__(256) void gemm2_mfma_k(
    const unsigned short* __restrict__ xsbf, const unsigned short* __restrict__ xsbr,
    const unsigned short* __restrict__ Wxbf, const unsigned short* __restrict__ Wxbr,
    float* __restrict__ part)
{
  __shared__ unsigned short At[128 * 32];
  __shared__ unsigned short Wt[64 * 32];
  const int tid  = threadIdx.x;
  const int w    = tid >> 6;
  const int lane = tid & 63;
  const int ks   = blockIdx.x;
  const int row0 = blockIdx.y * 128;
  const int dir  = blockIdx.z;
  const unsigned short* A = dir ? xsbr : xsbf;
  const unsigned short* W = dir ? Wxbr : Wxbf;
  const int kbase = ks * (DI_ / KS_);
  const int lrow  = lane >> 2;
  const int lkoff = (lane & 3) * 8;
  const int fr = lane & 15;
  const int fq = (lane >> 4) * 8;

  floatx4 acc[2][4];
#pragma unroll
  for (int i = 0; i < 2; ++i)
#pragma unroll
    for (int j = 0; j < 4; ++j)
#pragma unroll
      for (int r = 0; r < 4; ++r) acc[i][j][r] = 0.f;

  for (int k0 = 0; k0 < DI_ / KS_; k0 += 32) {
#pragma unroll
    for (int j = 0; j < 2; ++j) {
      int r = w * 32 + j * 16;
      gload_lds16(A + (size_t)(row0 + r + lrow) * DI_ + kbase + k0 + lkoff, At + r * 32);
    }
    {
      int r = w * 16;
      gload_lds16(W + (size_t)(r + lrow) * DI_ + kbase + k0 + lkoff, Wt + r * 32);
    }
    __syncthreads();
    short8 af[2], bf[4];
#pragma unroll
    for (int i = 0; i < 2; ++i)
      af[i] = *(const short8*)&At[(32 * w + 16 * i + fr) * 32 + fq];
#pragma unroll
    for (int j = 0; j < 4; ++j)
      bf[j] = *(const short8*)&Wt[(16 * j + fr) * 32 + fq];
#pragma unroll
    for (int i = 0; i < 2; ++i)
#pragma unroll
      for (int j = 0; j < 4; ++j)
        acc[i][j] = __builtin_amdgcn_mfma_f32_16x16x32_bf16(af[i], bf[j], acc[i][j], 0, 0, 0);
    __syncthreads();
  }
  float* dst = part + (((size_t)dir * KS_ + ks) * M_) * 64;
#pragma unroll
  for (int i = 0; i < 2; ++i) {
    int rg = row0 + 32 * w + 16 * i + ((lane >> 4) << 2);
#pragma unroll
    for (int j = 0; j < 4; ++j) {
      int cg = 16 * j + (lane & 15);
#pragma unroll
      for (int r = 0; r < 4; ++r)
        dst[(size_t)(rg + r) * 64 + cg] = acc[i][j][r];
    }
  }
}

// Reduce split-K partials: xd[dir][m][n] = sum_ks part[dir][ks][m][n]
__global__ __launch_bounds__(256) void reduce_part_k(
    const float* __restrict__ part, float* __restrict__ xdf, float* __restrict__ xdr)
{
  int g = blockIdx.x * 256 + threadIdx.x;
  int n4  = g & 15;
  int m   = (g >> 4) & (M_ - 1);
  int dir = g >> 16;
  const float* p = part + ((size_t)dir * KS_ * M_ + m) * 64 + n4 * 4;
  float4 s = make_float4(0.f, 0.f, 0.f, 0.f);
#pragma unroll
  for (int ks = 0; ks < KS_; ++ks) {
    float4 v = *(const float4*)(p + (size_t)ks * M_ * 64);
    s.x += v.x; s.y += v.y; s.z += v.z; s.w += v.w;
  }
  float* xd = dir ? xdr : xdf;
  *(float4*)(xd + (size_t)m * 64 + n4 * 4) = s;
}

// ---------------------------------------------------------------------------
// Fused fp32 -> bf16 cast of 7 tensors
// ---------------------------------------------------------------------------
struct CastArgs {
  const float* src[7];
  unsigned short* dst[7];
  int start[7];
  int n[7];
};

__global__ __launch_bounds__(256) void cast_multi_k(CastArgs a, int total4)
{
  int g = blockIdx.x * 256 + threadIdx.x;
  if (g >= total4) return;
  int e = g * 4;
#pragma unroll 1
  for (int s = 0; s < 7; ++s) {
    if (e < a.start[s] + a.n[s]) {
      int off = e - a.start[s];
      float4 v = *(const float4*)(a.src[s] + off);
      ushort4 o;
      o.x = f2bf(v.x); o.y = f2bf(v.y); o.z = f2bf(v.z); o.w = f2bf(v.w);
      *(ushort4*)(a.dst[s] + off) = o;
      return;
    }
  }
}

// ---------------------------------------------------------------------------
// GEMM3 (fp32, both dirs via grid.z): dt = softplus(xd[:, :32] . Wdt^T + dtb)
// ---------------------------------------------------------------------------
__global__ __launch_bounds__(256) void gemm3_k(
    const float* __restrict__ A0, const float* __restrict__ A1,
    const float* __restrict__ W0, const float* __restrict__ W1,
    const float* __restrict__ b0, const float* __restrict__ b1,
    float* __restrict__ C0, float* __restrict__ C1)
{
  const float* A = blockIdx.z ? A1 : A0;
  const float* W = blockIdx.z ? W1 : W0;
  const float* bias = blockIdx.z ? b1 : b0;
  float* C = blockIdx.z ? C1 : C0;
  const int K = DTR_, lda = 64, ldw = DTR_, ldc = DI_;
  __shared__ __align__(16) float As[16][68];
  __shared__ __align__(16) float Ws[16][68];
  const int tid = threadIdx.x;
  const int tx = tid & 15;
  const int ty = tid >> 4;
  const int row0 = blockIdx.y * 64;
  const int col0 = blockIdx.x * 64;
  const int lm = tid >> 2;
  const int lk = (tid & 3) << 2;
  float acc[4][4] = {};
  for (int k0 = 0; k0 < K; k0 += 16) {
    float4 av = *(const float4*)(A + (size_t)(row0 + lm) * lda + k0 + lk);
    float4 wv = *(const float4*)(W + (size_t)(col0 + lm) * ldw + k0 + lk);
    As[lk+0][lm] = av.x; As[lk+1][lm] = av.y; As[lk+2][lm] = av.z; As[lk+3][lm] = av.w;
    Ws[lk+0][lm] = wv.x; Ws[lk+1][lm] = wv.y; Ws[lk+2][lm] = wv.z; Ws[lk+3][lm] = wv.w;
    __syncthreads();
#pragma unroll
    for (int kk = 0; kk < 16; ++kk) {
      float4 a = *(const float4*)&As[kk][ty << 2];
      float4 b = *(const float4*)&Ws[kk][tx << 2];
      float aa[4] = {a.x, a.y, a.z, a.w};
      float bb[4] = {b.x, b.y, b.z, b.w};
#pragma unroll
      for (int i = 0; i < 4; ++i)
#pragma unroll
        for (int j = 0; j < 4; ++j)
          acc[i][j] = fmaf(aa[i], bb[j], acc[i][j]);
    }
    __syncthreads();
  }
#pragma unroll
  for (int i = 0; i < 4; ++i) {
    int m = row0 + (ty << 2) + i;
#pragma unroll
    for (int j = 0; j < 4; ++j) {
      int n = col0 + (tx << 2) + j;
      float v = acc[i][j] + bias[n];
      v = (v > 20.f) ? v : log1pf(__expf(v));
      C[(size_t)m * ldc + n] = v;
    }
  }
}

// ---------------------------------------------------------------------------
// Depthwise conv(4) + bias + SiLU, both directions; bf16 in (xz) / bf16 out.
// ---------------------------------------------------------------------------
__global__ __launch_bounds__(256) void conv_silu_k(
    const unsigned short* __restrict__ xzbf, const unsigned short* __restrict__ xzbr,
    const float* __restrict__ cwf, const float* __restrict__ cbf,
    const float* __restrict__ cwr, const float* __restrict__ cbr,
    unsigned short* __restrict__ xsbf, unsigned short* __restrict__ xsbr)
{
  int bid = blockIdx.x;                 // [dir][b][t]
  int t   = bid & (L_ - 1);
  int b   = (bid >> 11) & (B_ - 1);
  int dir = bid >> 12;
  const unsigned short* xz = dir ? xzbr : xzbf;
  const float* cw = dir ? cwr : cwf;
  const float* cb = dir ? cbr : cbf;
  unsigned short* xsb = dir ? xsbr : xsbf;
  int d0 = threadIdx.x << 2;
  float wv[4][4];
#pragma unroll
  for (int i = 0; i < 4; ++i) {
    float4 w4 = *(const float4*)(cw + (size_t)(d0 + i) * 4);
    wv[i][0] = w4.x; wv[i][1] = w4.y; wv[i][2] = w4.z; wv[i][3] = w4.w;
  }
  float4 cbv = *(const float4*)(cb + d0);
  float acc[4] = {cbv.x, cbv.y, cbv.z, cbv.w};
#pragma unroll
  for (int j = 0; j < 4; ++j) {
    int tt = dir ? (t + 3 - j) : (t - 3 + j);
    if (tt >= 0 && tt < L_) {
      ushort4 v = *(const ushort4*)(xz + ((size_t)b * L_ + tt) * 2048 + d0);
      acc[0] = fmaf(wv[0][j], bf2f(v.x), acc[0]);
      acc[1] = fmaf(wv[1][j], bf2f(v.y), acc[1]);
      acc[2] = fmaf(wv[2][j], bf2f(v.z), acc[2]);
      acc[3] = fmaf(wv[3][j], bf2f(v.w), acc[3]);
    }
  }
  float4 o;
  o.x = acc[0] * __builtin_amdgcn_rcpf(1.f + __expf(-acc[0]));
  o.y = acc[1] * __builtin_amdgcn_rcpf(1.f + __expf(-acc[1]));
  o.z = acc[2] * __builtin_amdgcn_rcpf(1.f + __expf(-acc[2]));
  o.w = acc[3] * __builtin_amdgcn_rcpf(1.f + __expf(-acc[3]));
  ushort4 ob;
  ob.x = f2bf(o.x); ob.y = f2bf(o.y); ob.z = f2bf(o.z); ob.w = f2bf(o.w);
  *(ushort4*)(xsb + ((size_t)b * L_ + t) * DI_ + d0) = ob;
}

// ---------------------------------------------------------------------------
// Scan pass A: per (dir,b,d,chunk): E = local end state, dts = sum dt.
// ---------------------------------------------------------------------------
__global__ __launch_bounds__(256) void scan_passA_k(
    const float* __restrict__ dtf, const float* __restrict__ dtr,
    const unsigned short* __restrict__ xsbf, const unsigned short* __restrict__ xsbr,
    const float* __restrict__ xdf, const float* __restrict__ xdr,
    const float* __restrict__ Alogf, const float* __restrict__ Alogr,
    float* __restrict__ E, float* __restrict__ dts)
{
  __shared__ float bS[CL_][16];         // B row per chunk step
  int bid  = blockIdx.x;               // [dir][b][c][dgrp]
  int dgrp = bid & 3;
  int c    = (bid >> 2) & (NC_ - 1);
  int b    = (bid >> 8) & 1;
  int dir  = bid >> 9;
  int d    = (dgrp << 8) + threadIdx.x;
  const float* dt = dir ? dtr : dtf;
  const unsigned short* xs = dir ? xsbr : xsbf;
  const float* xd = dir ? xdr : xdf;
  const float* Al = dir ? Alogr : Alogf;
  if (threadIdx.x < CL_ * 4) {
    int li = threadIdx.x >> 2;
    int lc = threadIdx.x & 3;
    *(float4*)&bS[li][lc * 4] =
        *(const float4*)(xd + ((size_t)b * L_ + c * CL_ + li) * 64 + 32 + lc * 4);
  }
  float Ai2[16];
#pragma unroll
  for (int s = 0; s < 16; ++s) Ai2[s] = -__expf(Al[(size_t)d * 16 + s]) * LOG2E_;
  float h[16];
#pragma unroll
  for (int s = 0; s < 16; ++s) h[s] = 0.f;
  int t0 = c * CL_ + (dir ? CL_ - 1 : 0);
  const long sdt = (dir ? -1L : 1L) * DI_;
  const float* dtp = dt + ((size_t)b * L_ + t0) * DI_ + d;
  const unsigned short* xsp = xs + ((size_t)b * L_ + t0) * DI_ + d;
  float dtsum = 0.f;
  __syncthreads();
#pragma unroll 2
  for (int i = 0; i < CL_; ++i) {
    int row = dir ? (CL_ - 1 - i) : i;
    float dtv = *dtp;
    float xv  = bf2f(*xsp);
    float Bv[16];
#pragma unroll
    for (int q = 0; q < 4; ++q) {
      float4 bq = *(const float4*)&bS[row][4 * q];
      Bv[4*q] = bq.x; Bv[4*q+1] = bq.y; Bv[4*q+2] = bq.z; Bv[4*q+3] = bq.w;
    }
    float dtx = dtv * xv;
    dtsum += dtv;
#pragma unroll
    for (int s = 0; s < 16; ++s) {
      float dA = fexp2(dtv * Ai2[s]);
      h[s] = fmaf(dA, h[s], dtx * Bv[s]);
    }
    dtp += sdt; xsp += sdt;
  }
  size_t base = ((((size_t)dir * B_ + b) * NC_ + c) * DI_ + d) * 16;
#pragma unroll
  for (int q = 0; q < 4; ++q)
    *(float4*)(E + base + q * 4) = make_float4(h[4*q], h[4*q+1], h[4*q+2], h[4*q+3]);
  dts[(((size_t)dir * B_ + b) * NC_ + c) * DI_ + d] = dtsum;
}

// ---------------------------------------------------------------------------
// Chunk prefix: Hin[c] = state entering chunk c. P recomputed from dtsum.
// ---------------------------------------------------------------------------
__global__ __launch_bounds__(256) void scan_prefix_k(
    const float* __restrict__ E, const float* __restrict__ dts,
    const float* __restrict__ Alogf, const float* __restrict__ Alogr,
    float* __restrict__ Hin)
{
  int gid = blockIdx.x * 256 + threadIdx.x;   // [dir][b][d][s]
  int s   = gid & 15;
  int d   = (gid >> 4) & (DI_ - 1);
  int b   = (gid >> 14) & 1;
  int dir = gid >> 15;
  const float* Al = dir ? Alogr : Alogf;
  float Ai2 = -__expf(Al[(size_t)d * 16 + s]) * LOG2E_;
  size_t eb  = (((size_t)dir * B_ + b) * NC_) * DI_ * 16 + (size_t)d * 16 + s;
  size_t db2 = (((size_t)dir * B_ + b) * NC_) * DI_ + d;
  float h = 0.f;
  if (!dir) {
    for (int c = 0; c < NC_; ++c) {
      size_t idx = eb + (size_t)c * DI_ * 16;
      Hin[idx] = h;
      float Pv = fexp2(dts[db2 + (size_t)c * DI_] * Ai2);
      h = fmaf(Pv, h, E[idx]);
    }
  } else {
    for (int c = NC_ - 1; c >= 0; --c) {
      size_t idx = eb + (size_t)c * DI_ * 16;
      Hin[idx] = h;
      float Pv = fexp2(dts[db2 + (size_t)c * DI_] * Ai2);
      h = fmaf(Pv, h, E[idx]);
    }
  }
}

// ---------------------------------------------------------------------------
// Scan pass C: replay chunk from Hin, y = (sum_s h*C + xs*Dp) * silu(z) -> bf16
// ---------------------------------------------------------------------------
__global__ __launch_bounds__(256) void scan_passC_k(
    const float* __restrict__ dtf, const float* __restrict__ dtr,
    const unsigned short* __restrict__ xsbf, const unsigned short* __restrict__ xsbr,
    const float* __restrict__ xdf, const float* __restrict__ xdr,
    const unsigned short* __restrict__ xzbf, const unsigned short* __restrict__ xzbr,
    const float* __restrict__ Alogf, const float* __restrict__ Alogr,
    const float* __restrict__ Dpf, const float* __restrict__ Dpr,
    const float* __restrict__ Hin,
    unsigned short* __restrict__ ybf, unsigned short* __restrict__ ybr)
{
  __shared__ float bcS[CL_][32];        // B(16)+C(16) per chunk step
  int bid  = blockIdx.x;
  int dgrp = bid & 3;
  int c    = (bid >> 2) & (NC_ - 1);
  int b    = (bid >> 8) & 1;
  int dir  = bid >> 9;
  int d    = (dgrp << 8) + threadIdx.x;
  const float* dt  = dir ? dtr : dtf;
  const unsigned short* xs = dir ? xsbr : xsbf;
  const float* xd  = dir ? xdr : xdf;
  const unsigned short* xz = dir ? xzbr : xzbf;
  const float* Al  = dir ? Alogr : Alogf;
  unsigned short* yb = dir ? ybr : ybf;
  float Dpv = (dir ? Dpr : Dpf)[d];
  {
    int li = threadIdx.x >> 3;
    int lc = threadIdx.x & 7;
    *(float4*)&bcS[li][lc * 4] =
        *(const float4*)(xd + ((size_t)b * L_ + c * CL_ + li) * 64 + 32 + lc * 4);
  }
  float Ai2[16];
#pragma unroll
  for (int s = 0; s < 16; ++s) Ai2[s] = -__expf(Al[(size_t)d * 16 + s]) * LOG2E_;
  size_t hb = ((((size_t)dir * B_ + b) * NC_ + c) * DI_ + d) * 16;
  float h[16];
#pragma unroll
  for (int q = 0; q < 4; ++q) {
    float4 hv = *(const float4*)(Hin + hb + q * 4);
    h[4*q] = hv.x; h[4*q+1] = hv.y; h[4*q+2] = hv.z; h[4*q+3] = hv.w;
  }
  int t0 = c * CL_ + (dir ? CL_ - 1 : 0);
  const long sdt = (dir ? -1L : 1L) * DI_;
  const long sz_ = (dir ? -1L : 1L) * 2048;
  const float* dtp = dt + ((size_t)b * L_ + t0) * DI_ + d;
  const unsigned short* xsp = xs + ((size_t)b * L_ + t0) * DI_ + d;
  const unsigned short* zp = xz + ((size_t)b * L_ + t0) * 2048 + DI_ + d;
  unsigned short* ybp = yb + ((size_t)b * L_ + t0) * DI_ + d;
  __syncthreads();
#pragma unroll 2
  for (int i = 0; i < CL_; ++i) {
    int row = dir ? (CL_ - 1 - i) : i;
    float dtv = *dtp;
    float xv  = bf2f(*xsp);
    float z   = bf2f(*zp);
    float Bv[16], Cv[16];
#pragma unroll
    for (int q = 0; q < 4; ++q) {
      float4 bq = *(const float4*)&bcS[row][4 * q];
      float4 cq = *(const float4*)&bcS[row][16 + 4 * q];
      Bv[4*q] = bq.x; Bv[4*q+1] = bq.y; Bv[4*q+2] = bq.z; Bv[4*q+3] = bq.w;
      Cv[4*q] = cq.x; Cv[4*q+1] = cq.y; Cv[4*q+2] = cq.z; Cv[4*q+3] = cq.w;
    }
    float dtx = dtv * xv;
    float yacc = 0.f;
#pragma unroll
    for (int s = 0; s < 16; ++s) {
      float dA = fexp2(dtv * Ai2[s]);
      h[s] = fmaf(dA, h[s], dtx * Bv[s]);
      yacc = fmaf(h[s], Cv[s], yacc);
    }
    float yv = fmaf(xv, Dpv, yacc);
    float sz = z * __builtin_amdgcn_rcpf(1.f + __expf(-z));
    *ybp = f2bf(yv * sz);
    dtp += sdt; xsp += sdt; zp += sz_; ybp += sdt;
  }
}

// ---------------------------------------------------------------------------
extern "C" void kernel_launch(void* const* d_in, const int* in_sizes, int n_in,
                              void* d_out, int out_size, void* d_ws, size_t ws_size,
                              hipStream_t stream)
{
  const float* x       = (const float*)d_in[0];
  const float* Win_f   = (const float*)d_in[1];
  const float* convw_f = (const float*)d_in[2];
  const float* convb_f = (const float*)d_in[3];
  const float* Wx_f    = (const float*)d_in[4];
  const float* Wdt_f   = (const float*)d_in[5];
  const float* dtb_f   = (const float*)d_in[6];
  const float* Alog_f  = (const float*)d_in[7];
  const float* Dp_f    = (const float*)d_in[8];
  const float* Wout_f  = (const float*)d_in[9];
  const float* Win_r   = (const float*)d_in[10];
  const float* convw_r = (const float*)d_in[11];
  const float* convb_r = (const float*)d_in[12];
  const float* Wx_r    = (const float*)d_in[13];
  const float* Wdt_r   = (const float*)d_in[14];
  const float* dtb_r   = (const float*)d_in[15];
  const float* Alog_r  = (const float*)d_in[16];
  const float* Dp_r    = (const float*)d_in[17];
  const float* Wout_r  = (const float*)d_in[18];
  float* out = (float*)d_out;

  float* ws  = (float*)d_ws;
  float* xdf = ws;
  float* xdr = xdf + (size_t)M_ * 64;
  float* dtf = xdr + (size_t)M_ * 64;
  float* dtr = dtf + (size_t)M_ * DI_;
  float* Eb  = dtr + (size_t)M_ * DI_;                   // alias: GEMM2/GEMM4 partials
  float* Hb  = Eb + (size_t)2 * B_ * NC_ * DI_ * 16;
  float* dtsb = Hb + (size_t)2 * B_ * NC_ * DI_ * 16;
  float* part2 = Eb;   // GEMM2 partials (4.2M floats), dead before E written
  float* part4 = Eb;   // GEMM4 partials (4.2M floats), E dead after prefix
  unsigned short* xzbf    = (unsigned short*)(dtsb + (size_t)2 * B_ * NC_ * DI_);
  unsigned short* xzbr    = xzbf + (size_t)M_ * 2048;
  unsigned short* xb      = xzbr + (size_t)M_ * 2048;
  unsigned short* Winb_f  = xb + (size_t)M_ * DM_;
  unsigned short* Winb_r  = Winb_f + (size_t)2048 * DM_;
  unsigned short* Woutb_f = Winb_r + (size_t)2048 * DM_;
  unsigned short* Woutb_r = Woutb_f + (size_t)DM_ * DI_;
  unsigned short* ybf     = Woutb_r + (size_t)DM_ * DI_;
  unsigned short* ybr     = ybf + (size_t)M_ * DI_;
  unsigned short* xsbf    = ybr + (size_t)M_ * DI_;
  unsigned short* xsbr    = xsbf + (size_t)M_ * DI_;
  unsigned short* Wxb_f   = xsbr + (size_t)M_ * DI_;
  unsigned short* Wxb_r   = Wxb_f + (size_t)64 * DI_;

  dim3 blk(256);

  // cast x, Win_f/r, Wout_f/r, Wx_f/r to bf16
  {
    CastArgs ca;
    ca.src[0] = x;      ca.dst[0] = xb;      ca.n[0] = M_ * DM_;
    ca.src[1] = Win_f;  ca.dst[1] = Winb_f;  ca.n[1] = 2048 * DM_;
    ca.src[2] = Win_r;  ca.dst[2] = Winb_r;  ca.n[2] = 2048 * DM_;
    ca.src[3] = Wout_f; ca.dst[3] = Woutb_f; ca.n[3] = DM_ * DI_;
    ca.src[4] = Wout_r; ca.dst[4] = Woutb_r; ca.n[4] = DM_ * DI_;
    ca.src[5] = Wx_f;   ca.dst[5] = Wxb_f;   ca.n[5] = 64 * DI_;
    ca.src[6] = Wx_r;   ca.dst[6] = Wxb_r;   ca.n[6] = 64 * DI_;
    int st = 0;
    for (int s = 0; s < 7; ++s) { ca.start[s] = st; st += ca.n[s]; }
    int total4 = st / 4;
    cast_multi_k<<<(total4 + 255) / 256, blk, 0, stream>>>(ca, total4);
  }

  // GEMM1 (bf16 MFMA, both dirs): xz = x . Win^T -> bf16
  gemm1_mfma_k<<<dim3(2048 / 128, M_ / 128, 2), blk, 0, stream>>>(
      xb, Winb_f, Winb_r, xzbf, xzbr, M_, 2048, DM_);

  // conv + silu (both dirs), bf16 in/out
  conv_silu_k<<<2 * B_ * L_, blk, 0, stream>>>(xzbf, xzbr, convw_f, convb_f,
      convw_r, convb_r, xsbf, xsbr);

  // GEMM2 (bf16 MFMA split-K, both dirs) + reduce
  gemm2_mfma_k<<<dim3(KS_, M_ / 128, 2), blk, 0, stream>>>(
      xsbf, xsbr, Wxb_f, Wxb_r, part2);
  reduce_part_k<<<(2 * M_ * 16) / 256, blk, 0, stream>>>(part2, xdf, xdr);

  // GEMM3 (fp32, both dirs): dt = softplus(x_dbl[:, :32] . Wdt^T + dtb)
  gemm3_k<<<dim3(DI_ / 64, M_ / 64, 2), blk, 0, stream>>>(
      xdf, xdr, Wdt_f, Wdt_r, dtb_f, dtb_r, dtf, dtr);

  // chunked scan (A -> prefix -> C), P recomputed from dtsum
  scan_passA_k<<<2 * B_ * NC_ * 4, blk, 0, stream>>>(dtf, dtr, xsbf, xsbr,
      xdf, xdr, Alog_f, Alog_r, Eb, dtsb);
  scan_prefix_k<<<(2 * B_ * DI_ * 16) / 256, blk, 0, stream>>>(
      Eb, dtsb, Alog_f, Alog_r, Hb);
  scan_passC_k<<<2 * B_ * NC_ * 4, blk, 0, stream>>>(dtf, dtr, xsbf, xsbr,
      xdf, xdr, xzbf, xzbr, Alog_f, Alog_r, Dp_f, Dp_r, Hb, ybf, ybr);

  // GEMM4 (bf16 MFMA, split-source partials) + add
  gemm4_mfma_k<<<dim3(DM_ / 64, M_ / 128, 2), blk, 0, stream>>>(
      ybf, Woutb_f, ybr, Woutb_r, part4);
  add2_k<<<(M_ * DM_ / 4) / 256, blk, 0, stream>>>(part4, out);
}

// Round 10
// 278.564 us; speedup vs baseline: 1.2036x; 1.0846x over previous
//
#include <hip/hip_runtime.h>
#include <cmath>

#define B_   2
#define L_   2048
#define DM_  512
#define DI_  1024
#define DS_  16
#define DTR_ 32
#define M_   (B_*L_)   // 4096
#define NC_  64        // chunks
#define CL_  32        // chunk length (NC_*CL_ == L_)
#define KS_  8         // GEMM2 split-K factor
#define LOG2E_ 1.44269504088896340736f
#define LN2_   0.69314718055994530942f

typedef __attribute__((ext_vector_type(8))) short short8;   // 8 bf16 = 4 VGPRs
typedef __attribute__((ext_vector_type(4))) float floatx4;  // MFMA acc

__device__ inline unsigned short f2bf(float f) {
  unsigned u = __float_as_uint(f);
  unsigned r = (u + 0x7fffu + ((u >> 16) & 1u)) >> 16;   // RNE
  return (unsigned short)r;
}
__device__ inline float bf2f(unsigned short u) {
  return __uint_as_float(((unsigned)u) << 16);
}
// raw v_exp_f32 (2^x) / v_log_f32 (log2 x) — libm exp2f/log1pf are slow multi-inst paths
__device__ inline float fexp2(float x) { return __builtin_amdgcn_exp2f(x); }
__device__ inline float flog2(float x) { return __builtin_amdgcn_logf(x); }

__device__ inline void gload_lds16(const unsigned short* g, unsigned short* l) {
  __builtin_amdgcn_global_load_lds(
      (const __attribute__((address_space(1))) void*)g,
      (__attribute__((address_space(3))) void*)l, 16, 0, 0);
}

// ---------------------------------------------------------------------------
// GEMM1 (bf16 MFMA, both dirs via grid.z): xz = x . Win^T, OUTPUT bf16.
// ---------------------------------------------------------------------------
__global__ __launch_bounds__(256) void gemm1_mfma_k(
    const unsigned short* __restrict__ A,
    const unsigned short* __restrict__ Wf, const unsigned short* __restrict__ Wr,
    unsigned short* __restrict__ Cf, unsigned short* __restrict__ Cr,
    int M, int N, int K)
{
  __shared__ unsigned short At[128 * 32];
  __shared__ unsigned short Wt[128 * 32];
  const unsigned short* W = blockIdx.z ? Wr : Wf;
  unsigned short* C = blockIdx.z ? Cr : Cf;
  const int tid  = threadIdx.x;
  const int w    = tid >> 6;
  const int lane = tid & 63;
  const int wm   = w >> 1, wn = w & 1;
  const int row0 = blockIdx.y * 128, col0 = blockIdx.x * 128;
  const int lrow  = lane >> 2;
  const int lkoff = (lane & 3) * 8;
  const int fr = lane & 15;
  const int fq = (lane >> 4) * 8;

  floatx4 acc[4][4];
#pragma unroll
  for (int i = 0; i < 4; ++i)
#pragma unroll
    for (int j = 0; j < 4; ++j)
#pragma unroll
      for (int r = 0; r < 4; ++r) acc[i][j][r] = 0.f;

  for (int k0 = 0; k0 < K; k0 += 32) {
#pragma unroll
    for (int j = 0; j < 2; ++j) {
      int r = w * 32 + j * 16;
      gload_lds16(A + (size_t)(row0 + r + lrow) * K + k0 + lkoff, At + r * 32);
      gload_lds16(W + (size_t)(col0 + r + lrow) * K + k0 + lkoff, Wt + r * 32);
    }
    __syncthreads();
    short8 af[4], bf[4];
#pragma unroll
    for (int i = 0; i < 4; ++i) {
      af[i] = *(const short8*)&At[(64 * wm + 16 * i + fr) * 32 + fq];
      bf[i] = *(const short8*)&Wt[(64 * wn + 16 * i + fr) * 32 + fq];
    }
#pragma unroll
    for (int i = 0; i < 4; ++i)
#pragma unroll
      for (int j = 0; j < 4; ++j)
        acc[i][j] = __builtin_amdgcn_mfma_f32_16x16x32_bf16(af[i], bf[j], acc[i][j], 0, 0, 0);
    __syncthreads();
  }
#pragma unroll
  for (int i = 0; i < 4; ++i) {
    int rg = row0 + 64 * wm + 16 * i + ((lane >> 4) << 2);
#pragma unroll
    for (int j = 0; j < 4; ++j) {
      int cg = col0 + 64 * wn + 16 * j + (lane & 15);
#pragma unroll
      for (int r = 0; r < 4; ++r)
        C[(size_t)(rg + r) * N + cg] = f2bf(acc[i][j][r]);
    }
  }
}

// ---------------------------------------------------------------------------
// GEMM4 (bf16 MFMA, split-source): partial[z] = y_z . Wout_z^T
// ---------------------------------------------------------------------------
__global__ __launch_bounds__(256) void gemm4_mfma_k(
    const unsigned short* __restrict__ ybf, const unsigned short* __restrict__ Woutbf,
    const unsigned short* __restrict__ ybr, const unsigned short* __restrict__ Woutbr,
    float* __restrict__ part)
{
  __shared__ unsigned short At[128 * 32];
  __shared__ unsigned short Wt[64 * 32];
  const int tid  = threadIdx.x;
  const int w    = tid >> 6;
  const int lane = tid & 63;
  const int col0 = blockIdx.x * 64;
  const int row0 = blockIdx.y * 128;
  const int z    = blockIdx.z;
  const unsigned short* A = z ? ybr : ybf;
  const unsigned short* W = z ? Woutbr : Woutbf;
  const int lrow  = lane >> 2;
  const int lkoff = (lane & 3) * 8;
  const int fr = lane & 15;
  const int fq = (lane >> 4) * 8;

  floatx4 acc[2][4];
#pragma unroll
  for (int i = 0; i < 2; ++i)
#pragma unroll
    for (int j = 0; j < 4; ++j)
#pragma unroll
      for (int r = 0; r < 4; ++r) acc[i][j][r] = 0.f;

  for (int k0 = 0; k0 < DI_; k0 += 32) {
#pragma unroll
    for (int j = 0; j < 2; ++j) {
      int r = w * 32 + j * 16;
      gload_lds16(A + (size_t)(row0 + r + lrow) * DI_ + k0 + lkoff, At + r * 32);
    }
    {
      int r = w * 16;
      gload_lds16(W + (size_t)(col0 + r + lrow) * DI_ + k0 + lkoff, Wt + r * 32);
    }
    __syncthreads();
    short8 af[2], bf[4];
#pragma unroll
    for (int i = 0; i < 2; ++i)
      af[i] = *(const short8*)&At[(32 * w + 16 * i + fr) * 32 + fq];
#pragma unroll
    for (int j = 0; j < 4; ++j)
      bf[j] = *(const short8*)&Wt[(16 * j + fr) * 32 + fq];
#pragma unroll
    for (int i = 0; i < 2; ++i)
#pragma unroll
      for (int j = 0; j < 4; ++j)
        acc[i][j] = __builtin_amdgcn_mfma_f32_16x16x32_bf16(af[i], bf[j], acc[i][j], 0, 0, 0);
    __syncthreads();
  }
  float* dst = part + (size_t)z * M_ * DM_;
#pragma unroll
  for (int i = 0; i < 2; ++i) {
    int rg = row0 + 32 * w + 16 * i + ((lane >> 4) << 2);
#pragma unroll
    for (int j = 0; j < 4; ++j) {
      int cg = col0 + 16 * j + (lane & 15);
#pragma unroll
      for (int r = 0; r < 4; ++r)
        dst[(size_t)(rg + r) * DM_ + cg] = acc[i][j][r];
    }
  }
}

// out = p0 + p1 (float4)
__global__ __launch_bounds__(256) void add2_k(
    const float* __restrict__ part, float* __restrict__ out)
{
  int g = blockIdx.x * 256 + threadIdx.x;
  float4 a = *(const float4*)(part + (size_t)g * 4);
  float4 b = *(const float4*)(part + (size_t)M_ * DM_ + (size_t)g * 4);
  float4 o = make_float4(a.x + b.x, a.y + b.y, a.z + b.z, a.w + b.w);
  *(float4*)(out + (size_t)g * 4) = o;
}

// ---------------------------------------------------------------------------
// GEMM2 (bf16 MFMA, split-K, both dirs): part[dir][ks][m][n].
// ---------------------------------------------------------------------------
__global__ __launch_bounds__(256) void gemm2_mfma_k(
    const unsigned short* __restrict__ xsbf, const unsigned short* __restrict__ xsbr,
    const unsigned short* __restrict__ Wxbf, const unsigned short* __restrict__ Wxbr,
    float* __restrict__ part)
{
  __shared__ unsigned short At[128 * 32];
  __shared__ unsigned short Wt[64 * 32];
  const int tid  = threadIdx.x;
  const int w    = tid >> 6;
  const int lane = tid & 63;
  const int ks   = blockIdx.x;
  const int row0 = blockIdx.y * 128;
  const int dir  = blockIdx.z;
  const unsigned short* A = dir ? xsbr : xsbf;
  const unsigned short* W = dir ? Wxbr : Wxbf;
  const int kbase = ks * (DI_ / KS_);
  const int lrow  = lane >> 2;
  const int lkoff = (lane & 3) * 8;
  const int fr = lane & 15;
  const int fq = (lane >> 4) * 8;

  floatx4 acc[2][4];
#pragma unroll
  for (int i = 0; i < 2; ++i)
#pragma unroll
    for (int j = 0; j < 4; ++j)
#pragma unroll
      for (int r = 0; r < 4; ++r) acc[i][j][r] = 0.f;

  for (int k0 = 0; k0 < DI_ / KS_; k0 += 32) {
#pragma unroll
    for (int j = 0; j < 2; ++j) {
      int r = w * 32 + j * 16;
      gload_lds16(A + (size_t)(row0 + r + lrow) * DI_ + kbase + k0 + lkoff, At + r * 32);
    }
    {
      int r = w * 16;
      gload_lds16(W + (size_t)(r + lrow) * DI_ + kbase + k0 + lkoff, Wt + r * 32);
    }
    __syncthreads();
    short8 af[2], bf[4];
#pragma unroll
    for (int i = 0; i < 2; ++i)
      af[i] = *(const short8*)&At[(32 * w + 16 * i + fr) * 32 + fq];
#pragma unroll
    for (int j = 0; j < 4; ++j)
      bf[j] = *(const short8*)&Wt[(16 * j + fr) * 32 + fq];
#pragma unroll
    for (int i = 0; i < 2; ++i)
#pragma unroll
      for (int j = 0; j < 4; ++j)
        acc[i][j] = __builtin_amdgcn_mfma_f32_16x16x32_bf16(af[i], bf[j], acc[i][j], 0, 0, 0);
    __syncthreads();
  }
  float* dst = part + (((size_t)dir * KS_ + ks) * M_) * 64;
#pragma unroll
  for (int i = 0; i < 2; ++i) {
    int rg = row0 + 32 * w + 16 * i + ((lane >> 4) << 2);
#pragma unroll
    for (int j = 0; j < 4; ++j) {
      int cg = 16 * j + (lane & 15);
#pragma unroll
      for (int r = 0; r < 4; ++r)
        dst[(size_t)(rg + r) * 64 + cg] = acc[i][j][r];
    }
  }
}

// Reduce split-K partials: xd[dir][m][n] = sum_ks part[dir][ks][m][n]
__global__ __launch_bounds__(256) void reduce_part_k(
    const float* __restrict__ part, float* __restrict__ xdf, float* __restrict__ xdr)
{
  int g = blockIdx.x * 256 + threadIdx.x;
  int n4  = g & 15;
  int m   = (g >> 4) & (M_ - 1);
  int dir = g >> 16;
  const float* p = part + ((size_t)dir * KS_ * M_ + m) * 64 + n4 * 4;
  float4 s = make_float4(0.f, 0.f, 0.f, 0.f);
#pragma unroll
  for (int ks = 0; ks < KS_; ++ks) {
    float4 v = *(const float4*)(p + (size_t)ks * M_ * 64);
    s.x += v.x; s.y += v.y; s.z += v.z; s.w += v.w;
  }
  float* xd = dir ? xdr : xdf;
  *(float4*)(xd + (size_t)m * 64 + n4 * 4) = s;
}

// ---------------------------------------------------------------------------
// Fused fp32 -> bf16 cast of 7 tensors
// ---------------------------------------------------------------------------
struct CastArgs {
  const float* src[7];
  unsigned short* dst[7];
  int start[7];
  int n[7];
};

__global__ __launch_bounds__(256) void cast_multi_k(CastArgs a, int total4)
{
  int g = blockIdx.x * 256 + threadIdx.x;
  if (g >= total4) return;
  int e = g * 4;
#pragma unroll 1
  for (int s = 0; s < 7; ++s) {
    if (e < a.start[s] + a.n[s]) {
      int off = e - a.start[s];
      float4 v = *(const float4*)(a.src[s] + off);
      ushort4 o;
      o.x = f2bf(v.x); o.y = f2bf(v.y); o.z = f2bf(v.z); o.w = f2bf(v.w);
      *(ushort4*)(a.dst[s] + off) = o;
      return;
    }
  }
}

// ---------------------------------------------------------------------------
// GEMM3 (fp32, both dirs via grid.z): dt = softplus(xd[:, :32] . Wdt^T + dtb)
// softplus via native v_exp_f32/v_log_f32: max(v,0) + ln2*log2(1+exp2(-|v|*log2e))
// ---------------------------------------------------------------------------
__global__ __launch_bounds__(256) void gemm3_k(
    const float* __restrict__ A0, const float* __restrict__ A1,
    const float* __restrict__ W0, const float* __restrict__ W1,
    const float* __restrict__ b0, const float* __restrict__ b1,
    float* __restrict__ C0, float* __restrict__ C1)
{
  const float* A = blockIdx.z ? A1 : A0;
  const float* W = blockIdx.z ? W1 : W0;
  const float* bias = blockIdx.z ? b1 : b0;
  float* C = blockIdx.z ? C1 : C0;
  const int K = DTR_, lda = 64, ldw = DTR_, ldc = DI_;
  __shared__ __align__(16) float As[16][68];
  __shared__ __align__(16) float Ws[16][68];
  const int tid = threadIdx.x;
  const int tx = tid & 15;
  const int ty = tid >> 4;
  const int row0 = blockIdx.y * 64;
  const int col0 = blockIdx.x * 64;
  const int lm = tid >> 2;
  const int lk = (tid & 3) << 2;
  float acc[4][4] = {};
  for (int k0 = 0; k0 < K; k0 += 16) {
    float4 av = *(const float4*)(A + (size_t)(row0 + lm) * lda + k0 + lk);
    float4 wv = *(const float4*)(W + (size_t)(col0 + lm) * ldw + k0 + lk);
    As[lk+0][lm] = av.x; As[lk+1][lm] = av.y; As[lk+2][lm] = av.z; As[lk+3][lm] = av.w;
    Ws[lk+0][lm] = wv.x; Ws[lk+1][lm] = wv.y; Ws[lk+2][lm] = wv.z; Ws[lk+3][lm] = wv.w;
    __syncthreads();
#pragma unroll
    for (int kk = 0; kk < 16; ++kk) {
      float4 a = *(const float4*)&As[kk][ty << 2];
      float4 b = *(const float4*)&Ws[kk][tx << 2];
      float aa[4] = {a.x, a.y, a.z, a.w};
      float bb[4] = {b.x, b.y, b.z, b.w};
#pragma unroll
      for (int i = 0; i < 4; ++i)
#pragma unroll
        for (int j = 0; j < 4; ++j)
          acc[i][j] = fmaf(aa[i], bb[j], acc[i][j]);
    }
    __syncthreads();
  }
#pragma unroll
  for (int i = 0; i < 4; ++i) {
    int m = row0 + (ty << 2) + i;
#pragma unroll
    for (int j = 0; j < 4; ++j) {
      int n = col0 + (tx << 2) + j;
      float v = acc[i][j] + bias[n];
      // stable softplus, native ops only
      float e = fexp2(-fabsf(v) * LOG2E_);
      float sp = fmaxf(v, 0.f) + LN2_ * flog2(1.f + e);
      C[(size_t)m * ldc + n] = sp;
    }
  }
}

// ---------------------------------------------------------------------------
// Depthwise conv(4) + bias + SiLU, both directions; bf16 in (xz) / bf16 out.
// ---------------------------------------------------------------------------
__global__ __launch_bounds__(256) void conv_silu_k(
    const unsigned short* __restrict__ xzbf, const unsigned short* __restrict__ xzbr,
    const float* __restrict__ cwf, const float* __restrict__ cbf,
    const float* __restrict__ cwr, const float* __restrict__ cbr,
    unsigned short* __restrict__ xsbf, unsigned short* __restrict__ xsbr)
{
  int bid = blockIdx.x;                 // [dir][b][t]
  int t   = bid & (L_ - 1);
  int b   = (bid >> 11) & (B_ - 1);
  int dir = bid >> 12;
  const unsigned short* xz = dir ? xzbr : xzbf;
  const float* cw = dir ? cwr : cwf;
  const float* cb = dir ? cbr : cbf;
  unsigned short* xsb = dir ? xsbr : xsbf;
  int d0 = threadIdx.x << 2;
  float wv[4][4];
#pragma unroll
  for (int i = 0; i < 4; ++i) {
    float4 w4 = *(const float4*)(cw + (size_t)(d0 + i) * 4);
    wv[i][0] = w4.x; wv[i][1] = w4.y; wv[i][2] = w4.z; wv[i][3] = w4.w;
  }
  float4 cbv = *(const float4*)(cb + d0);
  float acc[4] = {cbv.x, cbv.y, cbv.z, cbv.w};
#pragma unroll
  for (int j = 0; j < 4; ++j) {
    int tt = dir ? (t + 3 - j) : (t - 3 + j);
    if (tt >= 0 && tt < L_) {
      ushort4 v = *(const ushort4*)(xz + ((size_t)b * L_ + tt) * 2048 + d0);
      acc[0] = fmaf(wv[0][j], bf2f(v.x), acc[0]);
      acc[1] = fmaf(wv[1][j], bf2f(v.y), acc[1]);
      acc[2] = fmaf(wv[2][j], bf2f(v.z), acc[2]);
      acc[3] = fmaf(wv[3][j], bf2f(v.w), acc[3]);
    }
  }
  float4 o;
  o.x = acc[0] * __builtin_amdgcn_rcpf(1.f + fexp2(-acc[0] * LOG2E_));
  o.y = acc[1] * __builtin_amdgcn_rcpf(1.f + fexp2(-acc[1] * LOG2E_));
  o.z = acc[2] * __builtin_amdgcn_rcpf(1.f + fexp2(-acc[2] * LOG2E_));
  o.w = acc[3] * __builtin_amdgcn_rcpf(1.f + fexp2(-acc[3] * LOG2E_));
  ushort4 ob;
  ob.x = f2bf(o.x); ob.y = f2bf(o.y); ob.z = f2bf(o.z); ob.w = f2bf(o.w);
  *(ushort4*)(xsb + ((size_t)b * L_ + t) * DI_ + d0) = ob;
}

// ---------------------------------------------------------------------------
// Scan pass A: per (dir,b,d,chunk): E = local end state, dts = sum dt.
// ---------------------------------------------------------------------------
__global__ __launch_bounds__(256) void scan_passA_k(
    const float* __restrict__ dtf, const float* __restrict__ dtr,
    const unsigned short* __restrict__ xsbf, const unsigned short* __restrict__ xsbr,
    const float* __restrict__ xdf, const float* __restrict__ xdr,
    const float* __restrict__ Alogf, const float* __restrict__ Alogr,
    float* __restrict__ E, float* __restrict__ dts)
{
  __shared__ float bS[CL_][16];         // B row per chunk step
  int bid  = blockIdx.x;               // [dir][b][c][dgrp]
  int dgrp = bid & 3;
  int c    = (bid >> 2) & (NC_ - 1);
  int b    = (bid >> 8) & 1;
  int dir  = bid >> 9;
  int d    = (dgrp << 8) + threadIdx.x;
  const float* dt = dir ? dtr : dtf;
  const unsigned short* xs = dir ? xsbr : xsbf;
  const float* xd = dir ? xdr : xdf;
  const float* Al = dir ? Alogr : Alogf;
  if (threadIdx.x < CL_ * 4) {
    int li = threadIdx.x >> 2;
    int lc = threadIdx.x & 3;
    *(float4*)&bS[li][lc * 4] =
        *(const float4*)(xd + ((size_t)b * L_ + c * CL_ + li) * 64 + 32 + lc * 4);
  }
  float Ai2[16];
#pragma unroll
  for (int s = 0; s < 16; ++s) Ai2[s] = -__expf(Al[(size_t)d * 16 + s]) * LOG2E_;
  float h[16];
#pragma unroll
  for (int s = 0; s < 16; ++s) h[s] = 0.f;
  int t0 = c * CL_ + (dir ? CL_ - 1 : 0);
  const long sdt = (dir ? -1L : 1L) * DI_;
  const float* dtp = dt + ((size_t)b * L_ + t0) * DI_ + d;
  const unsigned short* xsp = xs + ((size_t)b * L_ + t0) * DI_ + d;
  float dtsum = 0.f;
  __syncthreads();
#pragma unroll 2
  for (int i = 0; i < CL_; ++i) {
    int row = dir ? (CL_ - 1 - i) : i;
    float dtv = *dtp;
    float xv  = bf2f(*xsp);
    float Bv[16];
#pragma unroll
    for (int q = 0; q < 4; ++q) {
      float4 bq = *(const float4*)&bS[row][4 * q];
      Bv[4*q] = bq.x; Bv[4*q+1] = bq.y; Bv[4*q+2] = bq.z; Bv[4*q+3] = bq.w;
    }
    float dtx = dtv * xv;
    dtsum += dtv;
#pragma unroll
    for (int s = 0; s < 16; ++s) {
      float dA = fexp2(dtv * Ai2[s]);
      h[s] = fmaf(dA, h[s], dtx * Bv[s]);
    }
    dtp += sdt; xsp += sdt;
  }
  size_t base = ((((size_t)dir * B_ + b) * NC_ + c) * DI_ + d) * 16;
#pragma unroll
  for (int q = 0; q < 4; ++q)
    *(float4*)(E + base + q * 4) = make_float4(h[4*q], h[4*q+1], h[4*q+2], h[4*q+3]);
  dts[(((size_t)dir * B_ + b) * NC_ + c) * DI_ + d] = dtsum;
}

// ---------------------------------------------------------------------------
// Chunk prefix: Hin[c] = state entering chunk c. P recomputed from dtsum.
// ---------------------------------------------------------------------------
__global__ __launch_bounds__(256) void scan_prefix_k(
    const float* __restrict__ E, const float* __restrict__ dts,
    const float* __restrict__ Alogf, const float* __restrict__ Alogr,
    float* __restrict__ Hin)
{
  int gid = blockIdx.x * 256 + threadIdx.x;   // [dir][b][d][s]
  int s   = gid & 15;
  int d   = (gid >> 4) & (DI_ - 1);
  int b   = (gid >> 14) & 1;
  int dir = gid >> 15;
  const float* Al = dir ? Alogr : Alogf;
  float Ai2 = -__expf(Al[(size_t)d * 16 + s]) * LOG2E_;
  size_t eb  = (((size_t)dir * B_ + b) * NC_) * DI_ * 16 + (size_t)d * 16 + s;
  size_t db2 = (((size_t)dir * B_ + b) * NC_) * DI_ + d;
  float h = 0.f;
  if (!dir) {
    for (int c = 0; c < NC_; ++c) {
      size_t idx = eb + (size_t)c * DI_ * 16;
      Hin[idx] = h;
      float Pv = fexp2(dts[db2 + (size_t)c * DI_] * Ai2);
      h = fmaf(Pv, h, E[idx]);
    }
  } else {
    for (int c = NC_ - 1; c >= 0; --c) {
      size_t idx = eb + (size_t)c * DI_ * 16;
      Hin[idx] = h;
      float Pv = fexp2(dts[db2 + (size_t)c * DI_] * Ai2);
      h = fmaf(Pv, h, E[idx]);
    }
  }
}

// ---------------------------------------------------------------------------
// Scan pass C: replay chunk from Hin, y = (sum_s h*C + xs*Dp) * silu(z) -> bf16
// ---------------------------------------------------------------------------
__global__ __launch_bounds__(256) void scan_passC_k(
    const float* __restrict__ dtf, const float* __restrict__ dtr,
    const unsigned short* __restrict__ xsbf, const unsigned short* __restrict__ xsbr,
    const float* __restrict__ xdf, const float* __restrict__ xdr,
    const unsigned short* __restrict__ xzbf, const unsigned short* __restrict__ xzbr,
    const float* __restrict__ Alogf, const float* __restrict__ Alogr,
    const float* __restrict__ Dpf, const float* __restrict__ Dpr,
    const float* __restrict__ Hin,
    unsigned short* __restrict__ ybf, unsigned short* __restrict__ ybr)
{
  __shared__ float bcS[CL_][32];        // B(16)+C(16) per chunk step
  int bid  = blockIdx.x;
  int dgrp = bid & 3;
  int c    = (bid >> 2) & (NC_ - 1);
  int b    = (bid >> 8) & 1;
  int dir  = bid >> 9;
  int d    = (dgrp << 8) + threadIdx.x;
  const float* dt  = dir ? dtr : dtf;
  const unsigned short* xs = dir ? xsbr : xsbf;
  const float* xd  = dir ? xdr : xdf;
  const unsigned short* xz = dir ? xzbr : xzbf;
  const float* Al  = dir ? Alogr : Alogf;
  unsigned short* yb = dir ? ybr : ybf;
  float Dpv = (dir ? Dpr : Dpf)[d];
  {
    int li = threadIdx.x >> 3;
    int lc = threadIdx.x & 7;
    *(float4*)&bcS[li][lc * 4] =
        *(const float4*)(xd + ((size_t)b * L_ + c * CL_ + li) * 64 + 32 + lc * 4);
  }
  float Ai2[16];
#pragma unroll
  for (int s = 0; s < 16; ++s) Ai2[s] = -__expf(Al[(size_t)d * 16 + s]) * LOG2E_;
  size_t hb = ((((size_t)dir * B_ + b) * NC_ + c) * DI_ + d) * 16;
  float h[16];
#pragma unroll
  for (int q = 0; q < 4; ++q) {
    float4 hv = *(const float4*)(Hin + hb + q * 4);
    h[4*q] = hv.x; h[4*q+1] = hv.y; h[4*q+2] = hv.z; h[4*q+3] = hv.w;
  }
  int t0 = c * CL_ + (dir ? CL_ - 1 : 0);
  const long sdt = (dir ? -1L : 1L) * DI_;
  const long sz_ = (dir ? -1L : 1L) * 2048;
  const float* dtp = dt + ((size_t)b * L_ + t0) * DI_ + d;
  const unsigned short* xsp = xs + ((size_t)b * L_ + t0) * DI_ + d;
  const unsigned short* zp = xz + ((size_t)b * L_ + t0) * 2048 + DI_ + d;
  unsigned short* ybp = yb + ((size_t)b * L_ + t0) * DI_ + d;
  __syncthreads();
#pragma unroll 2
  for (int i = 0; i < CL_; ++i) {
    int row = dir ? (CL_ - 1 - i) : i;
    float dtv = *dtp;
    float xv  = bf2f(*xsp);
    float z   = bf2f(*zp);
    float Bv[16], Cv[16];
#pragma unroll
    for (int q = 0; q < 4; ++q) {
      float4 bq = *(const float4*)&bcS[row][4 * q];
      float4 cq = *(const float4*)&bcS[row][16 + 4 * q];
      Bv[4*q] = bq.x; Bv[4*q+1] = bq.y; Bv[4*q+2] = bq.z; Bv[4*q+3] = bq.w;
      Cv[4*q] = cq.x; Cv[4*q+1] = cq.y; Cv[4*q+2] = cq.z; Cv[4*q+3] = cq.w;
    }
    float dtx = dtv * xv;
    float yacc = 0.f;
#pragma unroll
    for (int s = 0; s < 16; ++s) {
      float dA = fexp2(dtv * Ai2[s]);
      h[s] = fmaf(dA, h[s], dtx * Bv[s]);
      yacc = fmaf(h[s], Cv[s], yacc);
    }
    float yv = fmaf(xv, Dpv, yacc);
    float sz = z * __builtin_amdgcn_rcpf(1.f + fexp2(-z * LOG2E_));
    *ybp = f2bf(yv * sz);
    dtp += sdt; xsp += sdt; zp += sz_; ybp += sdt;
  }
}

// ---------------------------------------------------------------------------
extern "C" void kernel_launch(void* const* d_in, const int* in_sizes, int n_in,
                              void* d_out, int out_size, void* d_ws, size_t ws_size,
                              hipStream_t stream)
{
  const float* x       = (const float*)d_in[0];
  const float* Win_f   = (const float*)d_in[1];
  const float* convw_f = (const float*)d_in[2];
  const float* convb_f = (const float*)d_in[3];
  const float* Wx_f    = (const float*)d_in[4];
  const float* Wdt_f   = (const float*)d_in[5];
  const float* dtb_f   = (const float*)d_in[6];
  const float* Alog_f  = (const float*)d_in[7];
  const float* Dp_f    = (const float*)d_in[8];
  const float* Wout_f  = (const float*)d_in[9];
  const float* Win_r   = (const float*)d_in[10];
  const float* convw_r = (const float*)d_in[11];
  const float* convb_r = (const float*)d_in[12];
  const float* Wx_r    = (const float*)d_in[13];
  const float* Wdt_r   = (const float*)d_in[14];
  const float* dtb_r   = (const float*)d_in[15];
  const float* Alog_r  = (const float*)d_in[16];
  const float* Dp_r    = (const float*)d_in[17];
  const float* Wout_r  = (const float*)d_in[18];
  float* out = (float*)d_out;

  float* ws  = (float*)d_ws;
  float* xdf = ws;
  float* xdr = xdf + (size_t)M_ * 64;
  float* dtf = xdr + (size_t)M_ * 64;
  float* dtr = dtf + (size_t)M_ * DI_;
  float* Eb  = dtr + (size_t)M_ * DI_;                   // alias: GEMM2/GEMM4 partials
  float* Hb  = Eb + (size_t)2 * B_ * NC_ * DI_ * 16;
  float* dtsb = Hb + (size_t)2 * B_ * NC_ * DI_ * 16;
  float* part2 = Eb;   // GEMM2 partials (4.2M floats), dead before E written
  float* part4 = Eb;   // GEMM4 partials (4.2M floats), E dead after prefix
  unsigned short* xzbf    = (unsigned short*)(dtsb + (size_t)2 * B_ * NC_ * DI_);
  unsigned short* xzbr    = xzbf + (size_t)M_ * 2048;
  unsigned short* xb      = xzbr + (size_t)M_ * 2048;
  unsigned short* Winb_f  = xb + (size_t)M_ * DM_;
  unsigned short* Winb_r  = Winb_f + (size_t)2048 * DM_;
  unsigned short* Woutb_f = Winb_r + (size_t)2048 * DM_;
  unsigned short* Woutb_r = Woutb_f + (size_t)DM_ * DI_;
  unsigned short* ybf     = Woutb_r + (size_t)DM_ * DI_;
  unsigned short* ybr     = ybf + (size_t)M_ * DI_;
  unsigned short* xsbf    = ybr + (size_t)M_ * DI_;
  unsigned short* xsbr    = xsbf + (size_t)M_ * DI_;
  unsigned short* Wxb_f   = xsbr + (size_t)M_ * DI_;
  unsigned short* Wxb_r   = Wxb_f + (size_t)64 * DI_;

  dim3 blk(256);

  // cast x, Win_f/r, Wout_f/r, Wx_f/r to bf16
  {
    CastArgs ca;
    ca.src[0] = x;      ca.dst[0] = xb;      ca.n[0] = M_ * DM_;
    ca.src[1] = Win_f;  ca.dst[1] = Winb_f;  ca.n[1] = 2048 * DM_;
    ca.src[2] = Win_r;  ca.dst[2] = Winb_r;  ca.n[2] = 2048 * DM_;
    ca.src[3] = Wout_f; ca.dst[3] = Woutb_f; ca.n[3] = DM_ * DI_;
    ca.src[4] = Wout_r; ca.dst[4] = Woutb_r; ca.n[4] = DM_ * DI_;
    ca.src[5] = Wx_f;   ca.dst[5] = Wxb_f;   ca.n[5] = 64 * DI_;
    ca.src[6] = Wx_r;   ca.dst[6] = Wxb_r;   ca.n[6] = 64 * DI_;
    int st = 0;
    for (int s = 0; s < 7; ++s) { ca.start[s] = st; st += ca.n[s]; }
    int total4 = st / 4;
    cast_multi_k<<<(total4 + 255) / 256, blk, 0, stream>>>(ca, total4);
  }

  // GEMM1 (bf16 MFMA, both dirs): xz = x . Win^T -> bf16
  gemm1_mfma_k<<<dim3(2048 / 128, M_ / 128, 2), blk, 0, stream>>>(
      xb, Winb_f, Winb_r, xzbf, xzbr, M_, 2048, DM_);

  // conv + silu (both dirs), bf16 in/out
  conv_silu_k<<<2 * B_ * L_, blk, 0, stream>>>(xzbf, xzbr, convw_f, convb_f,
      convw_r, convb_r, xsbf, xsbr);

  // GEMM2 (bf16 MFMA split-K, both dirs) + reduce
  gemm2_mfma_k<<<dim3(KS_, M_ / 128, 2), blk, 0, stream>>>(
      xsbf, xsbr, Wxb_f, Wxb_r, part2);
  reduce_part_k<<<(2 * M_ * 16) / 256, blk, 0, stream>>>(part2, xdf, xdr);

  // GEMM3 (fp32, both dirs): dt = softplus(x_dbl[:, :32] . Wdt^T + dtb)
  gemm3_k<<<dim3(DI_ / 64, M_ / 64, 2), blk, 0, stream>>>(
      xdf, xdr, Wdt_f, Wdt_r, dtb_f, dtb_r, dtf, dtr);

  // chunked scan (A -> prefix -> C), P recomputed from dtsum
  scan_passA_k<<<2 * B_ * NC_ * 4, blk, 0, stream>>>(dtf, dtr, xsbf, xsbr,
      xdf, xdr, Alog_f, Alog_r, Eb, dtsb);
  scan_prefix_k<<<(2 * B_ * DI_ * 16) / 256, blk, 0, stream>>>(
      Eb, dtsb, Alog_f, Alog_r, Hb);
  scan_passC_k<<<2 * B_ * NC_ * 4, blk, 0, stream>>>(dtf, dtr, xsbf, xsbr,
      xdf, xdr, xzbf, xzbr, Alog_f, Alog_r, Dp_f, Dp_r, Hb, ybf, ybr);

  // GEMM4 (bf16 MFMA, split-source partials) + add
  gemm4_mfma_k<<<dim3(DM_ / 64, M_ / 128, 2), blk, 0, stream>>>(
      ybf, Woutb_f, ybr, Woutb_r, part4);
  add2_k<<<(M_ * DM_ / 4) / 256, blk, 0, stream>>>(part4, out);
}

// Round 11
// 275.897 us; speedup vs baseline: 1.2152x; 1.0097x over previous
//
#include <hip/hip_runtime.h>
#include <cmath>

#define B_   2
#define L_   2048
#define DM_  512
#define DI_  1024
#define DS_  16
#define DTR_ 32
#define M_   (B_*L_)   // 4096
#define NC_  64        // chunks
#define CL_  32        // chunk length (NC_*CL_ == L_)
#define KS_  8         // GEMM2 split-K factor
#define LOG2E_ 1.44269504088896340736f
#define LN2_   0.69314718055994530942f

typedef __attribute__((ext_vector_type(8))) short short8;   // 8 bf16 = 4 VGPRs
typedef __attribute__((ext_vector_type(4))) float floatx4;  // MFMA acc

__device__ inline unsigned short f2bf(float f) {
  unsigned u = __float_as_uint(f);
  unsigned r = (u + 0x7fffu + ((u >> 16) & 1u)) >> 16;   // RNE
  return (unsigned short)r;
}
__device__ inline float bf2f(unsigned short u) {
  return __uint_as_float(((unsigned)u) << 16);
}
// raw v_exp_f32 (2^x) / v_log_f32 (log2 x) — libm exp2f/log1pf are slow multi-inst paths
__device__ inline float fexp2(float x) { return __builtin_amdgcn_exp2f(x); }
__device__ inline float flog2(float x) { return __builtin_amdgcn_logf(x); }

__device__ inline void gload_lds16(const unsigned short* g, unsigned short* l) {
  __builtin_amdgcn_global_load_lds(
      (const __attribute__((address_space(1))) void*)g,
      (__attribute__((address_space(3))) void*)l, 16, 0, 0);
}

// ---------------------------------------------------------------------------
// GEMM1 (bf16 MFMA, both dirs via grid.z): xz = x . Win^T, OUTPUT bf16.
// ---------------------------------------------------------------------------
__global__ __launch_bounds__(256) void gemm1_mfma_k(
    const unsigned short* __restrict__ A,
    const unsigned short* __restrict__ Wf, const unsigned short* __restrict__ Wr,
    unsigned short* __restrict__ Cf, unsigned short* __restrict__ Cr,
    int M, int N, int K)
{
  __shared__ unsigned short At[128 * 32];
  __shared__ unsigned short Wt[128 * 32];
  const unsigned short* W = blockIdx.z ? Wr : Wf;
  unsigned short* C = blockIdx.z ? Cr : Cf;
  const int tid  = threadIdx.x;
  const int w    = tid >> 6;
  const int lane = tid & 63;
  const int wm   = w >> 1, wn = w & 1;
  const int row0 = blockIdx.y * 128, col0 = blockIdx.x * 128;
  const int lrow  = lane >> 2;
  const int lkoff = (lane & 3) * 8;
  const int fr = lane & 15;
  const int fq = (lane >> 4) * 8;

  floatx4 acc[4][4];
#pragma unroll
  for (int i = 0; i < 4; ++i)
#pragma unroll
    for (int j = 0; j < 4; ++j)
#pragma unroll
      for (int r = 0; r < 4; ++r) acc[i][j][r] = 0.f;

  for (int k0 = 0; k0 < K; k0 += 32) {
#pragma unroll
    for (int j = 0; j < 2; ++j) {
      int r = w * 32 + j * 16;
      gload_lds16(A + (size_t)(row0 + r + lrow) * K + k0 + lkoff, At + r * 32);
      gload_lds16(W + (size_t)(col0 + r + lrow) * K + k0 + lkoff, Wt + r * 32);
    }
    __syncthreads();
    short8 af[4], bf[4];
#pragma unroll
    for (int i = 0; i < 4; ++i) {
      af[i] = *(const short8*)&At[(64 * wm + 16 * i + fr) * 32 + fq];
      bf[i] = *(const short8*)&Wt[(64 * wn + 16 * i + fr) * 32 + fq];
    }
#pragma unroll
    for (int i = 0; i < 4; ++i)
#pragma unroll
      for (int j = 0; j < 4; ++j)
        acc[i][j] = __builtin_amdgcn_mfma_f32_16x16x32_bf16(af[i], bf[j], acc[i][j], 0, 0, 0);
    __syncthreads();
  }
#pragma unroll
  for (int i = 0; i < 4; ++i) {
    int rg = row0 + 64 * wm + 16 * i + ((lane >> 4) << 2);
#pragma unroll
    for (int j = 0; j < 4; ++j) {
      int cg = col0 + 64 * wn + 16 * j + (lane & 15);
#pragma unroll
      for (int r = 0; r < 4; ++r)
        C[(size_t)(rg + r) * N + cg] = f2bf(acc[i][j][r]);
    }
  }
}

// ---------------------------------------------------------------------------
// GEMM4 (bf16 MFMA, split-source): partial[z] = y_z . Wout_z^T
// ---------------------------------------------------------------------------
__global__ __launch_bounds__(256) void gemm4_mfma_k(
    const unsigned short* __restrict__ ybf, const unsigned short* __restrict__ Woutbf,
    const unsigned short* __restrict__ ybr, const unsigned short* __restrict__ Woutbr,
    float* __restrict__ part)
{
  __shared__ unsigned short At[128 * 32];
  __shared__ unsigned short Wt[64 * 32];
  const int tid  = threadIdx.x;
  const int w    = tid >> 6;
  const int lane = tid & 63;
  const int col0 = blockIdx.x * 64;
  const int row0 = blockIdx.y * 128;
  const int z    = blockIdx.z;
  const unsigned short* A = z ? ybr : ybf;
  const unsigned short* W = z ? Woutbr : Woutbf;
  const int lrow  = lane >> 2;
  const int lkoff = (lane & 3) * 8;
  const int fr = lane & 15;
  const int fq = (lane >> 4) * 8;

  floatx4 acc[2][4];
#pragma unroll
  for (int i = 0; i < 2; ++i)
#pragma unroll
    for (int j = 0; j < 4; ++j)
#pragma unroll
      for (int r = 0; r < 4; ++r) acc[i][j][r] = 0.f;

  for (int k0 = 0; k0 < DI_; k0 += 32) {
#pragma unroll
    for (int j = 0; j < 2; ++j) {
      int r = w * 32 + j * 16;
      gload_lds16(A + (size_t)(row0 + r + lrow) * DI_ + k0 + lkoff, At + r * 32);
    }
    {
      int r = w * 16;
      gload_lds16(W + (size_t)(col0 + r + lrow) * DI_ + k0 + lkoff, Wt + r * 32);
    }
    __syncthreads();
    short8 af[2], bf[4];
#pragma unroll
    for (int i = 0; i < 2; ++i)
      af[i] = *(const short8*)&At[(32 * w + 16 * i + fr) * 32 + fq];
#pragma unroll
    for (int j = 0; j < 4; ++j)
      bf[j] = *(const short8*)&Wt[(16 * j + fr) * 32 + fq];
#pragma unroll
    for (int i = 0; i < 2; ++i)
#pragma unroll
      for (int j = 0; j < 4; ++j)
        acc[i][j] = __builtin_amdgcn_mfma_f32_16x16x32_bf16(af[i], bf[j], acc[i][j], 0, 0, 0);
    __syncthreads();
  }
  float* dst = part + (size_t)z * M_ * DM_;
#pragma unroll
  for (int i = 0; i < 2; ++i) {
    int rg = row0 + 32 * w + 16 * i + ((lane >> 4) << 2);
#pragma unroll
    for (int j = 0; j < 4; ++j) {
      int cg = col0 + 16 * j + (lane & 15);
#pragma unroll
      for (int r = 0; r < 4; ++r)
        dst[(size_t)(rg + r) * DM_ + cg] = acc[i][j][r];
    }
  }
}

// out = p0 + p1 (float4)
__global__ __launch_bounds__(256) void add2_k(
    const float* __restrict__ part, float* __restrict__ out)
{
  int g = blockIdx.x * 256 + threadIdx.x;
  float4 a = *(const float4*)(part + (size_t)g * 4);
  float4 b = *(const float4*)(part + (size_t)M_ * DM_ + (size_t)g * 4);
  float4 o = make_float4(a.x + b.x, a.y + b.y, a.z + b.z, a.w + b.w);
  *(float4*)(out + (size_t)g * 4) = o;
}

// ---------------------------------------------------------------------------
// GEMM2 (bf16 MFMA, split-K, both dirs): part[dir][ks][m][n].
// ---------------------------------------------------------------------------
__global__ __launch_bounds__(256) void gemm2_mfma_k(
    const unsigned short* __restrict__ xsbf, const unsigned short* __restrict__ xsbr,
    const unsigned short* __restrict__ Wxbf, const unsigned short* __restrict__ Wxbr,
    float* __restrict__ part)
{
  __shared__ unsigned short At[128 * 32];
  __shared__ unsigned short Wt[64 * 32];
  const int tid  = threadIdx.x;
  const int w    = tid >> 6;
  const int lane = tid & 63;
  const int ks   = blockIdx.x;
  const int row0 = blockIdx.y * 128;
  const int dir  = blockIdx.z;
  const unsigned short* A = dir ? xsbr : xsbf;
  const unsigned short* W = dir ? Wxbr : Wxbf;
  const int kbase = ks * (DI_ / KS_);
  const int lrow  = lane >> 2;
  const int lkoff = (lane & 3) * 8;
  const int fr = lane & 15;
  const int fq = (lane >> 4) * 8;

  floatx4 acc[2][4];
#pragma unroll
  for (int i = 0; i < 2; ++i)
#pragma unroll
    for (int j = 0; j < 4; ++j)
#pragma unroll
      for (int r = 0; r < 4; ++r) acc[i][j][r] = 0.f;

  for (int k0 = 0; k0 < DI_ / KS_; k0 += 32) {
#pragma unroll
    for (int j = 0; j < 2; ++j) {
      int r = w * 32 + j * 16;
      gload_lds16(A + (size_t)(row0 + r + lrow) * DI_ + kbase + k0 + lkoff, At + r * 32);
    }
    {
      int r = w * 16;
      gload_lds16(W + (size_t)(r + lrow) * DI_ + kbase + k0 + lkoff, Wt + r * 32);
    }
    __syncthreads();
    short8 af[2], bf[4];
#pragma unroll
    for (int i = 0; i < 2; ++i)
      af[i] = *(const short8*)&At[(32 * w + 16 * i + fr) * 32 + fq];
#pragma unroll
    for (int j = 0; j < 4; ++j)
      bf[j] = *(const short8*)&Wt[(16 * j + fr) * 32 + fq];
#pragma unroll
    for (int i = 0; i < 2; ++i)
#pragma unroll
      for (int j = 0; j < 4; ++j)
        acc[i][j] = __builtin_amdgcn_mfma_f32_16x16x32_bf16(af[i], bf[j], acc[i][j], 0, 0, 0);
    __syncthreads();
  }
  float* dst = part + (((size_t)dir * KS_ + ks) * M_) * 64;
#pragma unroll
  for (int i = 0; i < 2; ++i) {
    int rg = row0 + 32 * w + 16 * i + ((lane >> 4) << 2);
#pragma unroll
    for (int j = 0; j < 4; ++j) {
      int cg = 16 * j + (lane & 15);
#pragma unroll
      for (int r = 0; r < 4; ++r)
        dst[(size_t)(rg + r) * 64 + cg] = acc[i][j][r];
    }
  }
}

// Reduce split-K partials: xd[dir][m][n] = sum_ks part[dir][ks][m][n].
// Also emits dt_raw (cols 0..31) as bf16 for the MFMA GEMM3.
__global__ __launch_bounds__(256) void reduce_part_k(
    const float* __restrict__ part, float* __restrict__ xdf, float* __restrict__ xdr,
    unsigned short* __restrict__ drbf, unsigned short* __restrict__ drbr)
{
  int g = blockIdx.x * 256 + threadIdx.x;
  int n4  = g & 15;
  int m   = (g >> 4) & (M_ - 1);
  int dir = g >> 16;
  const float* p = part + ((size_t)dir * KS_ * M_ + m) * 64 + n4 * 4;
  float4 s = make_float4(0.f, 0.f, 0.f, 0.f);
#pragma unroll
  for (int ks = 0; ks < KS_; ++ks) {
    float4 v = *(const float4*)(p + (size_t)ks * M_ * 64);
    s.x += v.x; s.y += v.y; s.z += v.z; s.w += v.w;
  }
  float* xd = dir ? xdr : xdf;
  *(float4*)(xd + (size_t)m * 64 + n4 * 4) = s;
  if (n4 < 8) {   // dt_raw columns 0..31 -> bf16
    unsigned short* dr = dir ? drbr : drbf;
    ushort4 o;
    o.x = f2bf(s.x); o.y = f2bf(s.y); o.z = f2bf(s.z); o.w = f2bf(s.w);
    *(ushort4*)(dr + (size_t)m * 32 + n4 * 4) = o;
  }
}

// ---------------------------------------------------------------------------
// Fused fp32 -> bf16 cast of 9 tensors
// ---------------------------------------------------------------------------
struct CastArgs {
  const float* src[9];
  unsigned short* dst[9];
  int start[9];
  int n[9];
};

__global__ __launch_bounds__(256) void cast_multi_k(CastArgs a, int total4)
{
  int g = blockIdx.x * 256 + threadIdx.x;
  if (g >= total4) return;
  int e = g * 4;
#pragma unroll 1
  for (int s = 0; s < 9; ++s) {
    if (e < a.start[s] + a.n[s]) {
      int off = e - a.start[s];
      float4 v = *(const float4*)(a.src[s] + off);
      ushort4 o;
      o.x = f2bf(v.x); o.y = f2bf(v.y); o.z = f2bf(v.z); o.w = f2bf(v.w);
      *(ushort4*)(a.dst[s] + off) = o;
      return;
    }
  }
}

// ---------------------------------------------------------------------------
// GEMM3 (bf16 MFMA, both dirs via grid.z): dt = softplus(dt_raw . Wdt^T + dtb)
// K=32 == one 16x16x32 MFMA. 128x128 tile, 4 waves x (4x4) tiles, one K-step.
// ---------------------------------------------------------------------------
__global__ __launch_bounds__(256) void gemm3_mfma_k(
    const unsigned short* __restrict__ drbf, const unsigned short* __restrict__ drbr,
    const unsigned short* __restrict__ Wdtbf, const unsigned short* __restrict__ Wdtbr,
    const float* __restrict__ b0, const float* __restrict__ b1,
    float* __restrict__ C0, float* __restrict__ C1)
{
  __shared__ unsigned short At[128 * 32];
  __shared__ unsigned short Wt[128 * 32];
  const unsigned short* A = blockIdx.z ? drbr : drbf;
  const unsigned short* W = blockIdx.z ? Wdtbr : Wdtbf;
  const float* bias = blockIdx.z ? b1 : b0;
  float* C = blockIdx.z ? C1 : C0;
  const int tid  = threadIdx.x;
  const int w    = tid >> 6;
  const int lane = tid & 63;
  const int wm   = w >> 1, wn = w & 1;
  const int row0 = blockIdx.y * 128, col0 = blockIdx.x * 128;
  const int lrow  = lane >> 2;
  const int lkoff = (lane & 3) * 8;
  const int fr = lane & 15;
  const int fq = (lane >> 4) * 8;

#pragma unroll
  for (int j = 0; j < 2; ++j) {
    int r = w * 32 + j * 16;
    gload_lds16(A + (size_t)(row0 + r + lrow) * DTR_ + lkoff, At + r * 32);
    gload_lds16(W + (size_t)(col0 + r + lrow) * DTR_ + lkoff, Wt + r * 32);
  }
  __syncthreads();
  short8 af[4], bf[4];
#pragma unroll
  for (int i = 0; i < 4; ++i) {
    af[i] = *(const short8*)&At[(64 * wm + 16 * i + fr) * 32 + fq];
    bf[i] = *(const short8*)&Wt[(64 * wn + 16 * i + fr) * 32 + fq];
  }
  floatx4 acc[4][4];
#pragma unroll
  for (int i = 0; i < 4; ++i)
#pragma unroll
    for (int j = 0; j < 4; ++j) {
#pragma unroll
      for (int r = 0; r < 4; ++r) acc[i][j][r] = 0.f;
      acc[i][j] = __builtin_amdgcn_mfma_f32_16x16x32_bf16(af[i], bf[j], acc[i][j], 0, 0, 0);
    }
#pragma unroll
  for (int i = 0; i < 4; ++i) {
    int rg = row0 + 64 * wm + 16 * i + ((lane >> 4) << 2);
#pragma unroll
    for (int j = 0; j < 4; ++j) {
      int cg = col0 + 64 * wn + 16 * j + (lane & 15);
      float bv = bias[cg];
#pragma unroll
      for (int r = 0; r < 4; ++r) {
        float v = acc[i][j][r] + bv;
        float e = fexp2(-fabsf(v) * LOG2E_);
        float sp = fmaxf(v, 0.f) + LN2_ * flog2(1.f + e);
        C[(size_t)(rg + r) * DI_ + cg] = sp;
      }
    }
  }
}

// ---------------------------------------------------------------------------
// Depthwise conv(4) + bias + SiLU, both directions; bf16 in (xz) / bf16 out.
// ---------------------------------------------------------------------------
__global__ __launch_bounds__(256) void conv_silu_k(
    const unsigned short* __restrict__ xzbf, const unsigned short* __restrict__ xzbr,
    const float* __restrict__ cwf, const float* __restrict__ cbf,
    const float* __restrict__ cwr, const float* __restrict__ cbr,
    unsigned short* __restrict__ xsbf, unsigned short* __restrict__ xsbr)
{
  int bid = blockIdx.x;                 // [dir][b][t]
  int t   = bid & (L_ - 1);
  int b   = (bid >> 11) & (B_ - 1);
  int dir = bid >> 12;
  const unsigned short* xz = dir ? xzbr : xzbf;
  const float* cw = dir ? cwr : cwf;
  const float* cb = dir ? cbr : cbf;
  unsigned short* xsb = dir ? xsbr : xsbf;
  int d0 = threadIdx.x << 2;
  float wv[4][4];
#pragma unroll
  for (int i = 0; i < 4; ++i) {
    float4 w4 = *(const float4*)(cw + (size_t)(d0 + i) * 4);
    wv[i][0] = w4.x; wv[i][1] = w4.y; wv[i][2] = w4.z; wv[i][3] = w4.w;
  }
  float4 cbv = *(const float4*)(cb + d0);
  float acc[4] = {cbv.x, cbv.y, cbv.z, cbv.w};
#pragma unroll
  for (int j = 0; j < 4; ++j) {
    int tt = dir ? (t + 3 - j) : (t - 3 + j);
    if (tt >= 0 && tt < L_) {
      ushort4 v = *(const ushort4*)(xz + ((size_t)b * L_ + tt) * 2048 + d0);
      acc[0] = fmaf(wv[0][j], bf2f(v.x), acc[0]);
      acc[1] = fmaf(wv[1][j], bf2f(v.y), acc[1]);
      acc[2] = fmaf(wv[2][j], bf2f(v.z), acc[2]);
      acc[3] = fmaf(wv[3][j], bf2f(v.w), acc[3]);
    }
  }
  float4 o;
  o.x = acc[0] * __builtin_amdgcn_rcpf(1.f + fexp2(-acc[0] * LOG2E_));
  o.y = acc[1] * __builtin_amdgcn_rcpf(1.f + fexp2(-acc[1] * LOG2E_));
  o.z = acc[2] * __builtin_amdgcn_rcpf(1.f + fexp2(-acc[2] * LOG2E_));
  o.w = acc[3] * __builtin_amdgcn_rcpf(1.f + fexp2(-acc[3] * LOG2E_));
  ushort4 ob;
  ob.x = f2bf(o.x); ob.y = f2bf(o.y); ob.z = f2bf(o.z); ob.w = f2bf(o.w);
  *(ushort4*)(xsb + ((size_t)b * L_ + t) * DI_ + d0) = ob;
}

// ---------------------------------------------------------------------------
// Scan pass A: per (dir,b,d,chunk): E = local end state, dts = sum dt.
// ---------------------------------------------------------------------------
__global__ __launch_bounds__(256) void scan_passA_k(
    const float* __restrict__ dtf, const float* __restrict__ dtr,
    const unsigned short* __restrict__ xsbf, const unsigned short* __restrict__ xsbr,
    const float* __restrict__ xdf, const float* __restrict__ xdr,
    const float* __restrict__ Alogf, const float* __restrict__ Alogr,
    float* __restrict__ E, float* __restrict__ dts)
{
  __shared__ float bS[CL_][16];         // B row per chunk step
  int bid  = blockIdx.x;               // [dir][b][c][dgrp]
  int dgrp = bid & 3;
  int c    = (bid >> 2) & (NC_ - 1);
  int b    = (bid >> 8) & 1;
  int dir  = bid >> 9;
  int d    = (dgrp << 8) + threadIdx.x;
  const float* dt = dir ? dtr : dtf;
  const unsigned short* xs = dir ? xsbr : xsbf;
  const float* xd = dir ? xdr : xdf;
  const float* Al = dir ? Alogr : Alogf;
  if (threadIdx.x < CL_ * 4) {
    int li = threadIdx.x >> 2;
    int lc = threadIdx.x & 3;
    *(float4*)&bS[li][lc * 4] =
        *(const float4*)(xd + ((size_t)b * L_ + c * CL_ + li) * 64 + 32 + lc * 4);
  }
  float Ai2[16];
#pragma unroll
  for (int s = 0; s < 16; ++s) Ai2[s] = -__expf(Al[(size_t)d * 16 + s]) * LOG2E_;
  float h[16];
#pragma unroll
  for (int s = 0; s < 16; ++s) h[s] = 0.f;
  int t0 = c * CL_ + (dir ? CL_ - 1 : 0);
  const long sdt = (dir ? -1L : 1L) * DI_;
  const float* dtp = dt + ((size_t)b * L_ + t0) * DI_ + d;
  const unsigned short* xsp = xs + ((size_t)b * L_ + t0) * DI_ + d;
  float dtsum = 0.f;
  __syncthreads();
#pragma unroll 2
  for (int i = 0; i < CL_; ++i) {
    int row = dir ? (CL_ - 1 - i) : i;
    float dtv = *dtp;
    float xv  = bf2f(*xsp);
    float Bv[16];
#pragma unroll
    for (int q = 0; q < 4; ++q) {
      float4 bq = *(const float4*)&bS[row][4 * q];
      Bv[4*q] = bq.x; Bv[4*q+1] = bq.y; Bv[4*q+2] = bq.z; Bv[4*q+3] = bq.w;
    }
    float dtx = dtv * xv;
    dtsum += dtv;
#pragma unroll
    for (int s = 0; s < 16; ++s) {
      float dA = fexp2(dtv * Ai2[s]);
      h[s] = fmaf(dA, h[s], dtx * Bv[s]);
    }
    dtp += sdt; xsp += sdt;
  }
  size_t base = ((((size_t)dir * B_ + b) * NC_ + c) * DI_ + d) * 16;
#pragma unroll
  for (int q = 0; q < 4; ++q)
    *(float4*)(E + base + q * 4) = make_float4(h[4*q], h[4*q+1], h[4*q+2], h[4*q+3]);
  dts[(((size_t)dir * B_ + b) * NC_ + c) * DI_ + d] = dtsum;
}

// ---------------------------------------------------------------------------
// Chunk prefix: Hin[c] = state entering chunk c. P recomputed from dtsum.
// ---------------------------------------------------------------------------
__global__ __launch_bounds__(256) void scan_prefix_k(
    const float* __restrict__ E, const float* __restrict__ dts,
    const float* __restrict__ Alogf, const float* __restrict__ Alogr,
    float* __restrict__ Hin)
{
  int gid = blockIdx.x * 256 + threadIdx.x;   // [dir][b][d][s]
  int s   = gid & 15;
  int d   = (gid >> 4) & (DI_ - 1);
  int b   = (gid >> 14) & 1;
  int dir = gid >> 15;
  const float* Al = dir ? Alogr : Alogf;
  float Ai2 = -__expf(Al[(size_t)d * 16 + s]) * LOG2E_;
  size_t eb  = (((size_t)dir * B_ + b) * NC_) * DI_ * 16 + (size_t)d * 16 + s;
  size_t db2 = (((size_t)dir * B_ + b) * NC_) * DI_ + d;
  float h = 0.f;
  if (!dir) {
    for (int c = 0; c < NC_; ++c) {
      size_t idx = eb + (size_t)c * DI_ * 16;
      Hin[idx] = h;
      float Pv = fexp2(dts[db2 + (size_t)c * DI_] * Ai2);
      h = fmaf(Pv, h, E[idx]);
    }
  } else {
    for (int c = NC_ - 1; c >= 0; --c) {
      size_t idx = eb + (size_t)c * DI_ * 16;
      Hin[idx] = h;
      float Pv = fexp2(dts[db2 + (size_t)c * DI_] * Ai2);
      h = fmaf(Pv, h, E[idx]);
    }
  }
}

// ---------------------------------------------------------------------------
// Scan pass C: replay chunk from Hin, y = (sum_s h*C + xs*Dp) * silu(z) -> bf16
// ---------------------------------------------------------------------------
__global__ __launch_bounds__(256) void scan_passC_k(
    const float* __restrict__ dtf, const float* __restrict__ dtr,
    const unsigned short* __restrict__ xsbf, const unsigned short* __restrict__ xsbr,
    const float* __restrict__ xdf, const float* __restrict__ xdr,
    const unsigned short* __restrict__ xzbf, const unsigned short* __restrict__ xzbr,
    const float* __restrict__ Alogf, const float* __restrict__ Alogr,
    const float* __restrict__ Dpf, const float* __restrict__ Dpr,
    const float* __restrict__ Hin,
    unsigned short* __restrict__ ybf, unsigned short* __restrict__ ybr)
{
  __shared__ float bcS[CL_][32];        // B(16)+C(16) per chunk step
  int bid  = blockIdx.x;
  int dgrp = bid & 3;
  int c    = (bid >> 2) & (NC_ - 1);
  int b    = (bid >> 8) & 1;
  int dir  = bid >> 9;
  int d    = (dgrp << 8) + threadIdx.x;
  const float* dt  = dir ? dtr : dtf;
  const unsigned short* xs = dir ? xsbr : xsbf;
  const float* xd  = dir ? xdr : xdf;
  const unsigned short* xz = dir ? xzbr : xzbf;
  const float* Al  = dir ? Alogr : Alogf;
  unsigned short* yb = dir ? ybr : ybf;
  float Dpv = (dir ? Dpr : Dpf)[d];
  {
    int li = threadIdx.x >> 3;
    int lc = threadIdx.x & 7;
    *(float4*)&bcS[li][lc * 4] =
        *(const float4*)(xd + ((size_t)b * L_ + c * CL_ + li) * 64 + 32 + lc * 4);
  }
  float Ai2[16];
#pragma unroll
  for (int s = 0; s < 16; ++s) Ai2[s] = -__expf(Al[(size_t)d * 16 + s]) * LOG2E_;
  size_t hb = ((((size_t)dir * B_ + b) * NC_ + c) * DI_ + d) * 16;
  float h[16];
#pragma unroll
  for (int q = 0; q < 4; ++q) {
    float4 hv = *(const float4*)(Hin + hb + q * 4);
    h[4*q] = hv.x; h[4*q+1] = hv.y; h[4*q+2] = hv.z; h[4*q+3] = hv.w;
  }
  int t0 = c * CL_ + (dir ? CL_ - 1 : 0);
  const long sdt = (dir ? -1L : 1L) * DI_;
  const long sz_ = (dir ? -1L : 1L) * 2048;
  const float* dtp = dt + ((size_t)b * L_ + t0) * DI_ + d;
  const unsigned short* xsp = xs + ((size_t)b * L_ + t0) * DI_ + d;
  const unsigned short* zp = xz + ((size_t)b * L_ + t0) * 2048 + DI_ + d;
  unsigned short* ybp = yb + ((size_t)b * L_ + t0) * DI_ + d;
  __syncthreads();
#pragma unroll 2
  for (int i = 0; i < CL_; ++i) {
    int row = dir ? (CL_ - 1 - i) : i;
    float dtv = *dtp;
    float xv  = bf2f(*xsp);
    float z   = bf2f(*zp);
    float Bv[16], Cv[16];
#pragma unroll
    for (int q = 0; q < 4; ++q) {
      float4 bq = *(const float4*)&bcS[row][4 * q];
      float4 cq = *(const float4*)&bcS[row][16 + 4 * q];
      Bv[4*q] = bq.x; Bv[4*q+1] = bq.y; Bv[4*q+2] = bq.z; Bv[4*q+3] = bq.w;
      Cv[4*q] = cq.x; Cv[4*q+1] = cq.y; Cv[4*q+2] = cq.z; Cv[4*q+3] = cq.w;
    }
    float dtx = dtv * xv;
    float yacc = 0.f;
#pragma unroll
    for (int s = 0; s < 16; ++s) {
      float dA = fexp2(dtv * Ai2[s]);
      h[s] = fmaf(dA, h[s], dtx * Bv[s]);
      yacc = fmaf(h[s], Cv[s], yacc);
    }
    float yv = fmaf(xv, Dpv, yacc);
    float sz = z * __builtin_amdgcn_rcpf(1.f + fexp2(-z * LOG2E_));
    *ybp = f2bf(yv * sz);
    dtp += sdt; xsp += sdt; zp += sz_; ybp += sdt;
  }
}

// ---------------------------------------------------------------------------
extern "C" void kernel_launch(void* const* d_in, const int* in_sizes, int n_in,
                              void* d_out, int out_size, void* d_ws, size_t ws_size,
                              hipStream_t stream)
{
  const float* x       = (const float*)d_in[0];
  const float* Win_f   = (const float*)d_in[1];
  const float* convw_f = (const float*)d_in[2];
  const float* convb_f = (const float*)d_in[3];
  const float* Wx_f    = (const float*)d_in[4];
  const float* Wdt_f   = (const float*)d_in[5];
  const float* dtb_f   = (const float*)d_in[6];
  const float* Alog_f  = (const float*)d_in[7];
  const float* Dp_f    = (const float*)d_in[8];
  const float* Wout_f  = (const float*)d_in[9];
  const float* Win_r   = (const float*)d_in[10];
  const float* convw_r = (const float*)d_in[11];
  const float* convb_r = (const float*)d_in[12];
  const float* Wx_r    = (const float*)d_in[13];
  const float* Wdt_r   = (const float*)d_in[14];
  const float* dtb_r   = (const float*)d_in[15];
  const float* Alog_r  = (const float*)d_in[16];
  const float* Dp_r    = (const float*)d_in[17];
  const float* Wout_r  = (const float*)d_in[18];
  float* out = (float*)d_out;

  float* ws  = (float*)d_ws;
  float* xdf = ws;
  float* xdr = xdf + (size_t)M_ * 64;
  float* dtf = xdr + (size_t)M_ * 64;
  float* dtr = dtf + (size_t)M_ * DI_;
  float* Eb  = dtr + (size_t)M_ * DI_;                   // alias: GEMM2/GEMM4 partials
  float* Hb  = Eb + (size_t)2 * B_ * NC_ * DI_ * 16;
  float* dtsb = Hb + (size_t)2 * B_ * NC_ * DI_ * 16;
  float* part2 = Eb;   // GEMM2 partials (4.2M floats), dead before E written
  float* part4 = Eb;   // GEMM4 partials (4.2M floats), E dead after prefix
  unsigned short* xzbf    = (unsigned short*)(dtsb + (size_t)2 * B_ * NC_ * DI_);
  unsigned short* xzbr    = xzbf + (size_t)M_ * 2048;
  unsigned short* xb      = xzbr + (size_t)M_ * 2048;
  unsigned short* Winb_f  = xb + (size_t)M_ * DM_;
  unsigned short* Winb_r  = Winb_f + (size_t)2048 * DM_;
  unsigned short* Woutb_f = Winb_r + (size_t)2048 * DM_;
  unsigned short* Woutb_r = Woutb_f + (size_t)DM_ * DI_;
  unsigned short* ybf     = Woutb_r + (size_t)DM_ * DI_;
  unsigned short* ybr     = ybf + (size_t)M_ * DI_;
  unsigned short* xsbf    = ybr + (size_t)M_ * DI_;
  unsigned short* xsbr    = xsbf + (size_t)M_ * DI_;
  unsigned short* Wxb_f   = xsbr + (size_t)M_ * DI_;
  unsigned short* Wxb_r   = Wxb_f + (size_t)64 * DI_;
  unsigned short* Wdtb_f  = Wxb_r + (size_t)64 * DI_;
  unsigned short* Wdtb_r  = Wdtb_f + (size_t)DI_ * DTR_;
  unsigned short* drbf    = Wdtb_r + (size_t)DI_ * DTR_;
  unsigned short* drbr    = drbf + (size_t)M_ * DTR_;

  dim3 blk(256);

  // cast x, Win_f/r, Wout_f/r, Wx_f/r, Wdt_f/r to bf16
  {
    CastArgs ca;
    ca.src[0] = x;      ca.dst[0] = xb;      ca.n[0] = M_ * DM_;
    ca.src[1] = Win_f;  ca.dst[1] = Winb_f;  ca.n[1] = 2048 * DM_;
    ca.src[2] = Win_r;  ca.dst[2] = Winb_r;  ca.n[2] = 2048 * DM_;
    ca.src[3] = Wout_f; ca.dst[3] = Woutb_f; ca.n[3] = DM_ * DI_;
    ca.src[4] = Wout_r; ca.dst[4] = Woutb_r; ca.n[4] = DM_ * DI_;
    ca.src[5] = Wx_f;   ca.dst[5] = Wxb_f;   ca.n[5] = 64 * DI_;
    ca.src[6] = Wx_r;   ca.dst[6] = Wxb_r;   ca.n[6] = 64 * DI_;
    ca.src[7] = Wdt_f;  ca.dst[7] = Wdtb_f;  ca.n[7] = DI_ * DTR_;
    ca.src[8] = Wdt_r;  ca.dst[8] = Wdtb_r;  ca.n[8] = DI_ * DTR_;
    int st = 0;
    for (int s = 0; s < 9; ++s) { ca.start[s] = st; st += ca.n[s]; }
    int total4 = st / 4;
    cast_multi_k<<<(total4 + 255) / 256, blk, 0, stream>>>(ca, total4);
  }

  // GEMM1 (bf16 MFMA, both dirs): xz = x . Win^T -> bf16
  gemm1_mfma_k<<<dim3(2048 / 128, M_ / 128, 2), blk, 0, stream>>>(
      xb, Winb_f, Winb_r, xzbf, xzbr, M_, 2048, DM_);

  // conv + silu (both dirs), bf16 in/out
  conv_silu_k<<<2 * B_ * L_, blk, 0, stream>>>(xzbf, xzbr, convw_f, convb_f,
      convw_r, convb_r, xsbf, xsbr);

  // GEMM2 (bf16 MFMA split-K, both dirs) + reduce (also emits dt_raw bf16)
  gemm2_mfma_k<<<dim3(KS_, M_ / 128, 2), blk, 0, stream>>>(
      xsbf, xsbr, Wxb_f, Wxb_r, part2);
  reduce_part_k<<<(2 * M_ * 16) / 256, blk, 0, stream>>>(part2, xdf, xdr,
      drbf, drbr);

  // GEMM3 (bf16 MFMA, both dirs): dt = softplus(dt_raw . Wdt^T + dtb)
  gemm3_mfma_k<<<dim3(DI_ / 128, M_ / 128, 2), blk, 0, stream>>>(
      drbf, drbr, Wdtb_f, Wdtb_r, dtb_f, dtb_r, dtf, dtr);

  // chunked scan (A -> prefix -> C), P recomputed from dtsum
  scan_passA_k<<<2 * B_ * NC_ * 4, blk, 0, stream>>>(dtf, dtr, xsbf, xsbr,
      xdf, xdr, Alog_f, Alog_r, Eb, dtsb);
  scan_prefix_k<<<(2 * B_ * DI_ * 16) / 256, blk, 0, stream>>>(
      Eb, dtsb, Alog_f, Alog_r, Hb);
  scan_passC_k<<<2 * B_ * NC_ * 4, blk, 0, stream>>>(dtf, dtr, xsbf, xsbr,
      xdf, xdr, xzbf, xzbr, Alog_f, Alog_r, Dp_f, Dp_r, Hb, ybf, ybr);

  // GEMM4 (bf16 MFMA, split-source partials) + add
  gemm4_mfma_k<<<dim3(DM_ / 64, M_ / 128, 2), blk, 0, stream>>>(
      ybf, Woutb_f, ybr, Woutb_r, part4);
  add2_k<<<(M_ * DM_ / 4) / 256, blk, 0, stream>>>(part4, out);
}